// Round 3
// baseline (2404.011 us; speedup 1.0000x reference)
//
#include <hip/hip_runtime.h>
#include <math.h>

#define BATCH 128
#define NNODE 400
#define HID   128
#define NN    (NNODE*NNODE)      // 160000
#define KSEL  32000              // int(NN*0.2)
#define EQCAP 1024
#define EPSF  1e-9f

// map float -> unsigned so that descending float order == descending unsigned order
__device__ __forceinline__ unsigned tokey(float f) {
  unsigned u = __float_as_uint(f);
  return (u & 0x80000000u) ? ~u : (u | 0x80000000u);
}

// ---------------------------------------------------------------------------
// Generic tiled fp32 GEMM: C[m,n] = act( sum_k A[m,k]*B[k,n] + bias[n] + Res )
// AT: A stored transposed (A[k*lda+m]); TS: store transposed (C[n*ldc+m])
// ---------------------------------------------------------------------------
template<bool AT, bool BIAS, bool RES, bool RELU, bool TS>
__global__ void __launch_bounds__(256) gemm32(
    const float* __restrict__ A, long sA, int lda,
    const float* __restrict__ B, long sB, int ldb,
    const float* __restrict__ bias,
    const float* __restrict__ Res, long sRes,
    float* __restrict__ C, long sC, int ldc,
    int M, int Nc, int K)
{
  __shared__ float As[32][33];
  __shared__ float Bs[32][33];
  const int bz = blockIdx.z;
  A += (size_t)bz * sA;
  B += (size_t)bz * sB;
  C += (size_t)bz * sC;
  const float* Rp = RES ? (Res + (size_t)bz * sRes) : nullptr;

  const int n0 = blockIdx.x * 32;
  const int m0 = blockIdx.y * 32;
  const int tid = threadIdx.x;
  const int tx = tid & 15, ty = tid >> 4;

  float acc[2][2] = {{0.f,0.f},{0.f,0.f}};

  for (int k0 = 0; k0 < K; k0 += 32) {
    for (int e = tid; e < 1024; e += 256) {
      int kk, mm;
      if (!AT) { mm = e >> 5; kk = e & 31; }   // global inner index = kk (coalesced)
      else     { kk = e >> 5; mm = e & 31; }   // global inner index = mm (coalesced)
      int m = m0 + mm, k = k0 + kk;
      float v = 0.f;
      if (m < M && k < K)
        v = AT ? A[(size_t)k * lda + m] : A[(size_t)m * lda + k];
      As[kk][mm] = v;
    }
    for (int e = tid; e < 1024; e += 256) {
      int kk = e >> 5, nn = e & 31;
      int k = k0 + kk, n = n0 + nn;
      float v = 0.f;
      if (k < K && n < Nc)
        v = B[(size_t)k * ldb + n];
      Bs[kk][nn] = v;
    }
    __syncthreads();
#pragma unroll
    for (int kk = 0; kk < 32; ++kk) {
      float a0 = As[kk][ty], a1 = As[kk][ty + 16];
      float b0 = Bs[kk][tx], b1 = Bs[kk][tx + 16];
      acc[0][0] += a0 * b0; acc[0][1] += a0 * b1;
      acc[1][0] += a1 * b0; acc[1][1] += a1 * b1;
    }
    __syncthreads();
  }

#pragma unroll
  for (int im = 0; im < 2; ++im) {
#pragma unroll
    for (int in = 0; in < 2; ++in) {
      int m = m0 + ty + im * 16;
      int n = n0 + tx + in * 16;
      if (m < M && n < Nc) {
        float v = acc[im][in];
        if (BIAS) v += bias[n];
        size_t loc = TS ? ((size_t)n * ldc + m) : ((size_t)m * ldc + n);
        if (RES) v += Rp[loc];
        if (RELU) v = fmaxf(v, 0.f);
        C[loc] = v;
      }
    }
  }
}

// ---------------------------------------------------------------------------
__global__ void init_k(int* eqcnt) {
  int t = threadIdx.x;
  if (t < BATCH) eqcnt[t] = 0;
}

__global__ void denom_k(const float* __restrict__ x, float* __restrict__ denom) {
  int b = threadIdx.x;
  if (b < BATCH) {
    float v = x[(size_t)b * NN];
    denom[b] = 0.5f * logf((1.0f + v + EPSF) / (1.0f - v + EPSF));
  }
}

__global__ void xf_k(const float* __restrict__ x, const float* __restrict__ denom,
                     float* __restrict__ xf) {
  size_t e = (size_t)blockIdx.x * 256 + threadIdx.x;
  if (e >= (size_t)BATCH * NN) return;
  int b = (int)(e / NN);
  float v = x[e];
  float t = 0.5f * logf((1.0f + v + EPSF) / (1.0f - v + EPSF));
  xf[e] = t / denom[b];
}

// x2 = xf + 0.5*(delta + delta^T) off-diagonal, in place over xf
__global__ void x2_k(float* __restrict__ xf, const float* __restrict__ dl) {
  size_t e = (size_t)blockIdx.x * 256 + threadIdx.x;
  if (e >= (size_t)BATCH * NN) return;
  int b = (int)(e / NN);
  int rem = (int)(e - (size_t)b * NN);
  int n = rem / NNODE, m = rem - n * NNODE;
  if (n == m) return;
  size_t base = (size_t)b * NN;
  float d = 0.5f * (dl[base + (size_t)n * NNODE + m] + dl[base + (size_t)m * NNODE + n]);
  xf[e] += d;
}

// exact radix-select of the KSEL-th largest value (4x8-bit passes)
__global__ void __launch_bounds__(256) topk_k(const float* __restrict__ x2,
                                              unsigned* __restrict__ tau,
                                              int* __restrict__ rrem) {
  __shared__ unsigned hist[256];
  __shared__ unsigned s_prefix;
  __shared__ int s_k;
  const int b = blockIdx.x;
  const float* p = x2 + (size_t)b * NN;
  const int tid = threadIdx.x;
  if (tid == 0) { s_prefix = 0u; s_k = KSEL; }
  __syncthreads();
  for (int pass = 0; pass < 4; ++pass) {
    hist[tid] = 0u;
    __syncthreads();
    int shift = 24 - 8 * pass;
    unsigned pmask = (pass == 0) ? 0u : (0xFFFFFFFFu << (shift + 8));
    unsigned prefix = s_prefix;
    for (int i = tid; i < NN; i += 256) {
      unsigned key = tokey(p[i]);
      if ((key & pmask) == prefix) atomicAdd(&hist[(key >> shift) & 255u], 1u);
    }
    __syncthreads();
    if (tid == 0) {
      int k = s_k;
      unsigned byte = 0u;
      for (int bin = 255; bin >= 0; --bin) {
        int c = (int)hist[bin];
        if (c >= k) { byte = (unsigned)bin; break; }
        k -= c;
      }
      s_prefix = prefix | (byte << shift);
      s_k = k;
    }
    __syncthreads();
  }
  if (tid == 0) { tau[b] = s_prefix; rrem[b] = s_k; }
}

// A = x2 where key > tau, else 0; gather indices of exact ties
__global__ void build_k(const float* __restrict__ x2, const unsigned* __restrict__ tau,
                        float* __restrict__ A, int* __restrict__ eqcnt,
                        int* __restrict__ eqidx) {
  size_t e = (size_t)blockIdx.x * 256 + threadIdx.x;
  if (e >= (size_t)BATCH * NN) return;
  int b = (int)(e / NN);
  int i = (int)(e - (size_t)b * NN);
  float v = x2[e];
  unsigned key = tokey(v);
  unsigned tk = tau[b];
  A[e] = (key > tk) ? v : 0.f;
  if (key == tk) {
    int p = atomicAdd(&eqcnt[b], 1);
    if (p < EQCAP) eqidx[b * EQCAP + p] = i;
  }
}

// include the first rrem tie elements in ascending flat-index order
__global__ void eqfix_k(float* __restrict__ A, const float* __restrict__ x2,
                        const int* __restrict__ eqcnt, const int* __restrict__ eqidx,
                        const int* __restrict__ rrem) {
  int b = blockIdx.x;
  int cnt = eqcnt[b]; if (cnt > EQCAP) cnt = EQCAP;
  int r = rrem[b];
  for (int t = threadIdx.x; t < cnt; t += 256) {
    int idx = eqidx[b * EQCAP + t];
    int rank = 0;
    for (int u = 0; u < cnt; ++u) rank += (eqidx[b * EQCAP + u] < idx) ? 1 : 0;
    if (rank < r) A[(size_t)b * NN + idx] = x2[(size_t)b * NN + idx];
  }
}

__global__ void diag_k(float* __restrict__ A) {
  int t = blockIdx.x * blockDim.x + threadIdx.x;
  if (t >= BATCH * NNODE) return;
  int b = t / NNODE, i = t - b * NNODE;
  size_t o = (size_t)b * NN + (size_t)i * NNODE + i;
  if (A[o] == 0.f) A[o] = 1.0f;
}

__global__ void deg_k(const float* __restrict__ A, float* __restrict__ dinv) {
  int t = blockIdx.x * blockDim.x + threadIdx.x;
  if (t >= BATCH * NNODE) return;
  int b = t / NNODE, j = t - b * NNODE;
  const float* p = A + (size_t)b * NN + j;
  float s = 0.f;
  for (int i = 0; i < NNODE; ++i) s += p[(size_t)i * NNODE];
  dinv[t] = (s == 0.f) ? 0.f : 1.0f / sqrtf(s);
}

__global__ void an_k(float* __restrict__ A, const float* __restrict__ dinv) {
  size_t e = (size_t)blockIdx.x * 256 + threadIdx.x;
  if (e >= (size_t)BATCH * NN) return;
  int b = (int)(e / NN);
  int rem = (int)(e - (size_t)b * NN);
  int i = rem / NNODE, j = rem - i * NNODE;
  A[e] *= dinv[b * NNODE + i] * dinv[b * NNODE + j];
}

__global__ void head_k(const float* __restrict__ h2, const float* __restrict__ fc_w,
                       const float* __restrict__ fc_b, float* __restrict__ out) {
  int b = blockIdx.x;
  int f = threadIdx.x;  // 128
  float s = 0.f;
  const float* p = h2 + (size_t)b * NNODE * HID + f;
  for (int j = 0; j < NNODE; ++j) s += p[(size_t)j * HID];
  float pv = fmaxf(s / (float)NNODE, 0.f);
  __shared__ float r0[128], r1[128];
  r0[f] = pv * fc_w[f * 2 + 0];
  r1[f] = pv * fc_w[f * 2 + 1];
  __syncthreads();
  for (int sft = 64; sft > 0; sft >>= 1) {
    if (f < sft) { r0[f] += r0[f + sft]; r1[f] += r1[f + sft]; }
    __syncthreads();
  }
  if (f == 0) {
    out[b * 2 + 0] = r0[0] + fc_b[0];
    out[b * 2 + 1] = r1[0] + fc_b[1];
  }
}

// ---------------------------------------------------------------------------
extern "C" void kernel_launch(void* const* d_in, const int* in_sizes, int n_in,
                              void* d_out, int out_size, void* d_ws, size_t ws_size,
                              hipStream_t stream) {
  // Reference dtypes are float32 — inputs are float32 buffers (bf16-rounded
  // VALUES, fp32 storage). Reading them as bf16 was the R1/R2 bug.
  const float* x      = (const float*)d_in[0];
  // d_in[1] = slength (int32, unused by reference)
  const float* enc1_w = (const float*)d_in[2];
  const float* enc1_b = (const float*)d_in[3];
  const float* enc2_w = (const float*)d_in[4];
  const float* enc2_b = (const float*)d_in[5];
  const float* dec2_w = (const float*)d_in[6];
  const float* dec2_b = (const float*)d_in[7];
  const float* dec1_w = (const float*)d_in[8];
  const float* dec1_b = (const float*)d_in[9];
  const float* gcn1_w = (const float*)d_in[10];
  const float* gcn1_b = (const float*)d_in[11];
  const float* gcn2_w = (const float*)d_in[12];
  const float* gcn2_b = (const float*)d_in[13];
  const float* fc_w   = (const float*)d_in[14];
  const float* fc_b   = (const float*)d_in[15];
  float* out = (float*)d_out;
  (void)in_sizes; (void)n_in; (void)out_size; (void)ws_size;

  float* ws = (float*)d_ws;
  size_t off = 0;
  auto take = [&](size_t n) { float* p = ws + off; off += (n + 63) & ~(size_t)63; return p; };
  float* xf   = take((size_t)BATCH * NN);          // xf -> x2 (in place)
  float* dl   = take((size_t)BATCH * NN);          // delta -> A -> An (in place)
  float* o1   = take((size_t)BATCH * HID * NNODE); // out1 -> out2b (in place)
  float* o2   = take((size_t)BATCH * HID * HID);
  float* xw   = take((size_t)BATCH * NNODE * HID); // XW -> t (reused)
  float* hbuf = take((size_t)BATCH * NNODE * HID); // h -> h2 (reused)
  float* denom = take(BATCH);
  float* dinv  = take((size_t)BATCH * NNODE);
  unsigned* tau = (unsigned*)take(BATCH);
  int* rrem  = (int*)take(BATCH);
  int* eqcnt = (int*)take(BATCH);
  int* eqidx = (int*)take((size_t)BATCH * EQCAP);

  const size_t TOT = (size_t)BATCH * NN;
  const int EW_BLK = (int)((TOT + 255) / 256);

  init_k<<<1, 256, 0, stream>>>(eqcnt);
  denom_k<<<1, BATCH, 0, stream>>>(x, denom);
  xf_k<<<EW_BLK, 256, 0, stream>>>(x, denom, xf);

  // G1: out1[h,i] = relu(xf @ enc1_w + b)^T    M=400 N=128 K=400, trans-store
  gemm32<false, true, false, true, true><<<dim3(4, 13, BATCH), 256, 0, stream>>>(
      xf, NN, NNODE, enc1_w, 0, HID, enc1_b, nullptr, 0,
      o1, (long)HID * NNODE, NNODE, NNODE, HID, NNODE);
  // G2: out2 = relu(out1 @ enc2_w + b)         M=128 N=128 K=400
  gemm32<false, true, false, true, false><<<dim3(4, 4, BATCH), 256, 0, stream>>>(
      o1, (long)HID * NNODE, NNODE, enc2_w, 0, HID, enc2_b, nullptr, 0,
      o2, (long)HID * HID, HID, HID, HID, NNODE);
  // G3: out2b = relu(out2 @ dec2_w + b + out1) M=128 N=400 K=128, in-place into o1
  gemm32<false, true, true, true, false><<<dim3(13, 4, BATCH), 256, 0, stream>>>(
      o2, (long)HID * HID, HID, dec2_w, 0, NNODE, dec2_b,
      o1, (long)HID * NNODE,
      o1, (long)HID * NNODE, NNODE, HID, NNODE, HID);
  // G4: delta[n,m] = sum_h out2b[h,n]*dec1_w[h,m] + b   (AT)  M=400 N=400 K=128
  gemm32<true, true, false, false, false><<<dim3(13, 13, BATCH), 256, 0, stream>>>(
      o1, (long)HID * NNODE, NNODE, dec1_w, 0, NNODE, dec1_b, nullptr, 0,
      dl, NN, NNODE, NNODE, NNODE, HID);

  x2_k<<<EW_BLK, 256, 0, stream>>>(xf, dl);

  topk_k<<<BATCH, 256, 0, stream>>>(xf, tau, rrem);
  build_k<<<EW_BLK, 256, 0, stream>>>(xf, tau, dl, eqcnt, eqidx);
  eqfix_k<<<BATCH, 256, 0, stream>>>(dl, xf, eqcnt, eqidx, rrem);
  diag_k<<<(BATCH * NNODE + 255) / 256, 256, 0, stream>>>(dl);
  deg_k<<<(BATCH * NNODE + 255) / 256, 256, 0, stream>>>(dl, dinv);
  an_k<<<EW_BLK, 256, 0, stream>>>(dl, dinv);

  // G5: XW = x2 @ gcn1_w                       M=400 N=128 K=400
  gemm32<false, false, false, false, false><<<dim3(4, 13, BATCH), 256, 0, stream>>>(
      xf, NN, NNODE, gcn1_w, 0, HID, nullptr, nullptr, 0,
      xw, (long)NNODE * HID, HID, NNODE, HID, NNODE);
  // G6: h = relu(An^T @ XW + gcn1_b)           (AT, batched B)
  gemm32<true, true, false, true, false><<<dim3(4, 13, BATCH), 256, 0, stream>>>(
      dl, NN, NNODE, xw, (long)NNODE * HID, HID, gcn1_b, nullptr, 0,
      hbuf, (long)NNODE * HID, HID, NNODE, HID, NNODE);
  // G7: t = h @ gcn2_w                         M=400 N=128 K=128 (into xw)
  gemm32<false, false, false, false, false><<<dim3(4, 13, BATCH), 256, 0, stream>>>(
      hbuf, (long)NNODE * HID, HID, gcn2_w, 0, HID, nullptr, nullptr, 0,
      xw, (long)NNODE * HID, HID, NNODE, HID, HID);
  // G8: h2 = An^T @ t + gcn2_b                 (AT, batched B, into hbuf)
  gemm32<true, true, false, false, false><<<dim3(4, 13, BATCH), 256, 0, stream>>>(
      dl, NN, NNODE, xw, (long)NNODE * HID, HID, gcn2_b, nullptr, 0,
      hbuf, (long)NNODE * HID, HID, NNODE, HID, NNODE);

  head_k<<<BATCH, HID, 0, stream>>>(hbuf, fc_w, fc_b, out);
}

// Round 4
// 1722.922 us; speedup vs baseline: 1.3953x; 1.3953x over previous
//
#include <hip/hip_runtime.h>
#include <math.h>

#define BATCH 128
#define NNODE 400
#define HID   128
#define NN    (NNODE*NNODE)      // 160000
#define KSEL  32000              // int(NN*0.2)
#define EQCAP 1024
#define EPSF  1e-9f
#define TSPLIT 8                 // histogram blocks per sample
#define SEG   (NN / TSPLIT)      // 20000 (divisible by 4)

// map float -> unsigned so that descending float order == descending unsigned order
__device__ __forceinline__ unsigned tokey(float f) {
  unsigned u = __float_as_uint(f);
  return (u & 0x80000000u) ? ~u : (u | 0x80000000u);
}

// ---------------------------------------------------------------------------
// Generic tiled fp32 GEMM: C[m,n] = act( sum_k A[m,k]*B[k,n] + bias[n] + Res )
// AT: A stored transposed (A[k*lda+m]); TS: store transposed (C[n*ldc+m])
// ---------------------------------------------------------------------------
template<bool AT, bool BIAS, bool RES, bool RELU, bool TS>
__global__ void __launch_bounds__(256) gemm32(
    const float* __restrict__ A, long sA, int lda,
    const float* __restrict__ B, long sB, int ldb,
    const float* __restrict__ bias,
    const float* __restrict__ Res, long sRes,
    float* __restrict__ C, long sC, int ldc,
    int M, int Nc, int K)
{
  __shared__ float As[32][33];
  __shared__ float Bs[32][33];
  const int bz = blockIdx.z;
  A += (size_t)bz * sA;
  B += (size_t)bz * sB;
  C += (size_t)bz * sC;
  const float* Rp = RES ? (Res + (size_t)bz * sRes) : nullptr;

  const int n0 = blockIdx.x * 32;
  const int m0 = blockIdx.y * 32;
  const int tid = threadIdx.x;
  const int tx = tid & 15, ty = tid >> 4;

  float acc[2][2] = {{0.f,0.f},{0.f,0.f}};

  for (int k0 = 0; k0 < K; k0 += 32) {
    for (int e = tid; e < 1024; e += 256) {
      int kk, mm;
      if (!AT) { mm = e >> 5; kk = e & 31; }   // global inner index = kk (coalesced)
      else     { kk = e >> 5; mm = e & 31; }   // global inner index = mm (coalesced)
      int m = m0 + mm, k = k0 + kk;
      float v = 0.f;
      if (m < M && k < K)
        v = AT ? A[(size_t)k * lda + m] : A[(size_t)m * lda + k];
      As[kk][mm] = v;
    }
    for (int e = tid; e < 1024; e += 256) {
      int kk = e >> 5, nn = e & 31;
      int k = k0 + kk, n = n0 + nn;
      float v = 0.f;
      if (k < K && n < Nc)
        v = B[(size_t)k * ldb + n];
      Bs[kk][nn] = v;
    }
    __syncthreads();
#pragma unroll
    for (int kk = 0; kk < 32; ++kk) {
      float a0 = As[kk][ty], a1 = As[kk][ty + 16];
      float b0 = Bs[kk][tx], b1 = Bs[kk][tx + 16];
      acc[0][0] += a0 * b0; acc[0][1] += a0 * b1;
      acc[1][0] += a1 * b0; acc[1][1] += a1 * b1;
    }
    __syncthreads();
  }

#pragma unroll
  for (int im = 0; im < 2; ++im) {
#pragma unroll
    for (int in = 0; in < 2; ++in) {
      int m = m0 + ty + im * 16;
      int n = n0 + tx + in * 16;
      if (m < M && n < Nc) {
        float v = acc[im][in];
        if (BIAS) v += bias[n];
        size_t loc = TS ? ((size_t)n * ldc + m) : ((size_t)m * ldc + n);
        if (RES) v += Rp[loc];
        if (RELU) v = fmaxf(v, 0.f);
        C[loc] = v;
      }
    }
  }
}

// ---------------------------------------------------------------------------
__global__ void denom_k(const float* __restrict__ x, float* __restrict__ denom) {
  int b = threadIdx.x;
  if (b < BATCH) {
    float v = x[(size_t)b * NN];
    denom[b] = 0.5f * logf((1.0f + v + EPSF) / (1.0f - v + EPSF));
  }
}

__global__ void xf_k(const float* __restrict__ x, const float* __restrict__ denom,
                     float* __restrict__ xf) {
  size_t e = (size_t)blockIdx.x * 256 + threadIdx.x;
  if (e >= (size_t)BATCH * NN) return;
  int b = (int)(e / NN);
  float v = x[e];
  float t = 0.5f * logf((1.0f + v + EPSF) / (1.0f - v + EPSF));
  xf[e] = t / denom[b];
}

// x2 = xf + 0.5*(delta + delta^T) off-diagonal, in place over xf
__global__ void x2_k(float* __restrict__ xf, const float* __restrict__ dl) {
  size_t e = (size_t)blockIdx.x * 256 + threadIdx.x;
  if (e >= (size_t)BATCH * NN) return;
  int b = (int)(e / NN);
  int rem = (int)(e - (size_t)b * NN);
  int n = rem / NNODE, m = rem - n * NNODE;
  if (n == m) return;
  size_t base = (size_t)b * NN;
  float d = 0.5f * (dl[base + (size_t)n * NNODE + m] + dl[base + (size_t)m * NNODE + n]);
  xf[e] += d;
}

// ---------------------------------------------------------------------------
// Split top-k radix select. State: ghist[B][256], sprefix[B], sk[B].
// ---------------------------------------------------------------------------
__global__ void tz_init(unsigned* __restrict__ ghist, unsigned* __restrict__ sprefix,
                        int* __restrict__ sk, int* __restrict__ eqcnt) {
  int t = blockIdx.x * 256 + threadIdx.x;
  if (t < BATCH * 256) ghist[t] = 0u;
  if (t < BATCH) { sprefix[t] = 0u; sk[t] = KSEL; eqcnt[t] = 0; }
}

template<int PASS>
__global__ void __launch_bounds__(256) thist(const float* __restrict__ x2,
                                             const unsigned* __restrict__ sprefix,
                                             unsigned* __restrict__ ghist) {
  constexpr int shift = 24 - 8 * PASS;
  __shared__ unsigned h[8][256];   // 8 replicas to cut same-bin serialization
  const int b  = blockIdx.y;
  const int sb = blockIdx.x;
  const int tid = threadIdx.x;
  for (int i = tid; i < 8 * 256; i += 256) ((unsigned*)h)[i] = 0u;
  __syncthreads();

  const unsigned prefix = (PASS == 0) ? 0u : sprefix[b];
  const unsigned pmask  = (PASS == 0) ? 0u : (0xFFFFFFFFu << (shift + 8));
  const int rep = tid & 7;
  const float4* p4 = (const float4*)(x2 + (size_t)b * NN);
  const int i0 = sb * (SEG / 4), i1 = i0 + (SEG / 4);
  for (int i = i0 + tid; i < i1; i += 256) {
    float4 v = p4[i];
    unsigned k0 = tokey(v.x), k1 = tokey(v.y), k2 = tokey(v.z), k3 = tokey(v.w);
    if ((k0 & pmask) == prefix) atomicAdd(&h[rep][(k0 >> shift) & 255u], 1u);
    if ((k1 & pmask) == prefix) atomicAdd(&h[rep][(k1 >> shift) & 255u], 1u);
    if ((k2 & pmask) == prefix) atomicAdd(&h[rep][(k2 >> shift) & 255u], 1u);
    if ((k3 & pmask) == prefix) atomicAdd(&h[rep][(k3 >> shift) & 255u], 1u);
  }
  __syncthreads();
  if (tid < 256) {
    unsigned s = h[0][tid] + h[1][tid] + h[2][tid] + h[3][tid]
               + h[4][tid] + h[5][tid] + h[6][tid] + h[7][tid];
    if (s) atomicAdd(&ghist[b * 256 + tid], s);
  }
}

template<int PASS>
__global__ void __launch_bounds__(256) tpick(unsigned* __restrict__ ghist,
                                             unsigned* __restrict__ sprefix,
                                             int* __restrict__ sk,
                                             unsigned* __restrict__ tau,
                                             int* __restrict__ rrem) {
  constexpr int shift = 24 - 8 * PASS;
  const int b = blockIdx.x;
  __shared__ unsigned h[256];
  h[threadIdx.x] = ghist[b * 256 + threadIdx.x];
  __syncthreads();
  if (threadIdx.x == 0) {
    int k = sk[b];
    unsigned byte = 0u;
    for (int bin = 255; bin >= 0; --bin) {
      int c = (int)h[bin];
      if (c >= k) { byte = (unsigned)bin; break; }
      k -= c;
    }
    unsigned np = sprefix[b] | (byte << shift);
    sprefix[b] = np; sk[b] = k;
    if (PASS == 3) { tau[b] = np; rrem[b] = k; }
  }
  ghist[b * 256 + threadIdx.x] = 0u;   // ready for next pass
}

// A = x2 where key > tau, else 0; gather indices of exact ties
__global__ void build_k(const float* __restrict__ x2, const unsigned* __restrict__ tau,
                        float* __restrict__ A, int* __restrict__ eqcnt,
                        int* __restrict__ eqidx) {
  size_t e = (size_t)blockIdx.x * 256 + threadIdx.x;
  if (e >= (size_t)BATCH * NN) return;
  int b = (int)(e / NN);
  int i = (int)(e - (size_t)b * NN);
  float v = x2[e];
  unsigned key = tokey(v);
  unsigned tk = tau[b];
  A[e] = (key > tk) ? v : 0.f;
  if (key == tk) {
    int p = atomicAdd(&eqcnt[b], 1);
    if (p < EQCAP) eqidx[b * EQCAP + p] = i;
  }
}

// include the first rrem tie elements in ascending flat-index order
__global__ void eqfix_k(float* __restrict__ A, const float* __restrict__ x2,
                        const int* __restrict__ eqcnt, const int* __restrict__ eqidx,
                        const int* __restrict__ rrem) {
  int b = blockIdx.x;
  int cnt = eqcnt[b]; if (cnt > EQCAP) cnt = EQCAP;
  int r = rrem[b];
  for (int t = threadIdx.x; t < cnt; t += 256) {
    int idx = eqidx[b * EQCAP + t];
    int rank = 0;
    for (int u = 0; u < cnt; ++u) rank += (eqidx[b * EQCAP + u] < idx) ? 1 : 0;
    if (rank < r) A[(size_t)b * NN + idx] = x2[(size_t)b * NN + idx];
  }
}

__global__ void diag_k(float* __restrict__ A) {
  int t = blockIdx.x * blockDim.x + threadIdx.x;
  if (t >= BATCH * NNODE) return;
  int b = t / NNODE, i = t - b * NNODE;
  size_t o = (size_t)b * NN + (size_t)i * NNODE + i;
  if (A[o] == 0.f) A[o] = 1.0f;
}

__global__ void deg_k(const float* __restrict__ A, float* __restrict__ dinv) {
  int t = blockIdx.x * blockDim.x + threadIdx.x;
  if (t >= BATCH * NNODE) return;
  int b = t / NNODE, j = t - b * NNODE;
  const float* p = A + (size_t)b * NN + j;
  float s = 0.f;
  for (int i = 0; i < NNODE; ++i) s += p[(size_t)i * NNODE];
  dinv[t] = (s == 0.f) ? 0.f : 1.0f / sqrtf(s);
}

__global__ void an_k(float* __restrict__ A, const float* __restrict__ dinv) {
  size_t e = (size_t)blockIdx.x * 256 + threadIdx.x;
  if (e >= (size_t)BATCH * NN) return;
  int b = (int)(e / NN);
  int rem = (int)(e - (size_t)b * NN);
  int i = rem / NNODE, j = rem - i * NNODE;
  A[e] *= dinv[b * NNODE + i] * dinv[b * NNODE + j];
}

__global__ void head_k(const float* __restrict__ h2, const float* __restrict__ fc_w,
                       const float* __restrict__ fc_b, float* __restrict__ out) {
  int b = blockIdx.x;
  int f = threadIdx.x;  // 128
  float s = 0.f;
  const float* p = h2 + (size_t)b * NNODE * HID + f;
  for (int j = 0; j < NNODE; ++j) s += p[(size_t)j * HID];
  float pv = fmaxf(s / (float)NNODE, 0.f);
  __shared__ float r0[128], r1[128];
  r0[f] = pv * fc_w[f * 2 + 0];
  r1[f] = pv * fc_w[f * 2 + 1];
  __syncthreads();
  for (int sft = 64; sft > 0; sft >>= 1) {
    if (f < sft) { r0[f] += r0[f + sft]; r1[f] += r1[f + sft]; }
    __syncthreads();
  }
  if (f == 0) {
    out[b * 2 + 0] = r0[0] + fc_b[0];
    out[b * 2 + 1] = r1[0] + fc_b[1];
  }
}

// ---------------------------------------------------------------------------
extern "C" void kernel_launch(void* const* d_in, const int* in_sizes, int n_in,
                              void* d_out, int out_size, void* d_ws, size_t ws_size,
                              hipStream_t stream) {
  const float* x      = (const float*)d_in[0];
  // d_in[1] = slength (int32, unused by reference)
  const float* enc1_w = (const float*)d_in[2];
  const float* enc1_b = (const float*)d_in[3];
  const float* enc2_w = (const float*)d_in[4];
  const float* enc2_b = (const float*)d_in[5];
  const float* dec2_w = (const float*)d_in[6];
  const float* dec2_b = (const float*)d_in[7];
  const float* dec1_w = (const float*)d_in[8];
  const float* dec1_b = (const float*)d_in[9];
  const float* gcn1_w = (const float*)d_in[10];
  const float* gcn1_b = (const float*)d_in[11];
  const float* gcn2_w = (const float*)d_in[12];
  const float* gcn2_b = (const float*)d_in[13];
  const float* fc_w   = (const float*)d_in[14];
  const float* fc_b   = (const float*)d_in[15];
  float* out = (float*)d_out;
  (void)in_sizes; (void)n_in; (void)out_size; (void)ws_size;

  float* ws = (float*)d_ws;
  size_t off = 0;
  auto take = [&](size_t n) { float* p = ws + off; off += (n + 63) & ~(size_t)63; return p; };
  float* xf   = take((size_t)BATCH * NN);          // xf -> x2 (in place)
  float* dl   = take((size_t)BATCH * NN);          // delta -> A -> An (in place)
  float* o1   = take((size_t)BATCH * HID * NNODE); // out1 -> out2b (in place)
  float* o2   = take((size_t)BATCH * HID * HID);
  float* xw   = take((size_t)BATCH * NNODE * HID); // XW -> t (reused)
  float* hbuf = take((size_t)BATCH * NNODE * HID); // h -> h2 (reused)
  float* denom = take(BATCH);
  float* dinv  = take((size_t)BATCH * NNODE);
  unsigned* tau = (unsigned*)take(BATCH);
  int* rrem  = (int*)take(BATCH);
  int* eqcnt = (int*)take(BATCH);
  int* eqidx = (int*)take((size_t)BATCH * EQCAP);
  unsigned* ghist   = (unsigned*)take((size_t)BATCH * 256);
  unsigned* sprefix = (unsigned*)take(BATCH);
  int*      sk      = (int*)take(BATCH);

  const size_t TOT = (size_t)BATCH * NN;
  const int EW_BLK = (int)((TOT + 255) / 256);

  tz_init<<<128, 256, 0, stream>>>(ghist, sprefix, sk, eqcnt);
  denom_k<<<1, BATCH, 0, stream>>>(x, denom);
  xf_k<<<EW_BLK, 256, 0, stream>>>(x, denom, xf);

  // G1: out1[h,i] = relu(xf @ enc1_w + b)^T    M=400 N=128 K=400, trans-store
  gemm32<false, true, false, true, true><<<dim3(4, 13, BATCH), 256, 0, stream>>>(
      xf, NN, NNODE, enc1_w, 0, HID, enc1_b, nullptr, 0,
      o1, (long)HID * NNODE, NNODE, NNODE, HID, NNODE);
  // G2: out2 = relu(out1 @ enc2_w + b)         M=128 N=128 K=400
  gemm32<false, true, false, true, false><<<dim3(4, 4, BATCH), 256, 0, stream>>>(
      o1, (long)HID * NNODE, NNODE, enc2_w, 0, HID, enc2_b, nullptr, 0,
      o2, (long)HID * HID, HID, HID, HID, NNODE);
  // G3: out2b = relu(out2 @ dec2_w + b + out1) M=128 N=400 K=128, in-place into o1
  gemm32<false, true, true, true, false><<<dim3(13, 4, BATCH), 256, 0, stream>>>(
      o2, (long)HID * HID, HID, dec2_w, 0, NNODE, dec2_b,
      o1, (long)HID * NNODE,
      o1, (long)HID * NNODE, NNODE, HID, NNODE, HID);
  // G4: delta[n,m] = sum_h out2b[h,n]*dec1_w[h,m] + b   (AT)  M=400 N=400 K=128
  gemm32<true, true, false, false, false><<<dim3(13, 13, BATCH), 256, 0, stream>>>(
      o1, (long)HID * NNODE, NNODE, dec1_w, 0, NNODE, dec1_b, nullptr, 0,
      dl, NN, NNODE, NNODE, NNODE, HID);

  x2_k<<<EW_BLK, 256, 0, stream>>>(xf, dl);

  // split top-k radix select (replaces monolithic topk_k: was 789 us @ 5.8% occupancy)
  thist<0><<<dim3(TSPLIT, BATCH), 256, 0, stream>>>(xf, sprefix, ghist);
  tpick<0><<<BATCH, 256, 0, stream>>>(ghist, sprefix, sk, tau, rrem);
  thist<1><<<dim3(TSPLIT, BATCH), 256, 0, stream>>>(xf, sprefix, ghist);
  tpick<1><<<BATCH, 256, 0, stream>>>(ghist, sprefix, sk, tau, rrem);
  thist<2><<<dim3(TSPLIT, BATCH), 256, 0, stream>>>(xf, sprefix, ghist);
  tpick<2><<<BATCH, 256, 0, stream>>>(ghist, sprefix, sk, tau, rrem);
  thist<3><<<dim3(TSPLIT, BATCH), 256, 0, stream>>>(xf, sprefix, ghist);
  tpick<3><<<BATCH, 256, 0, stream>>>(ghist, sprefix, sk, tau, rrem);

  build_k<<<EW_BLK, 256, 0, stream>>>(xf, tau, dl, eqcnt, eqidx);
  eqfix_k<<<BATCH, 256, 0, stream>>>(dl, xf, eqcnt, eqidx, rrem);
  diag_k<<<(BATCH * NNODE + 255) / 256, 256, 0, stream>>>(dl);
  deg_k<<<(BATCH * NNODE + 255) / 256, 256, 0, stream>>>(dl, dinv);
  an_k<<<EW_BLK, 256, 0, stream>>>(dl, dinv);

  // G5: XW = x2 @ gcn1_w                       M=400 N=128 K=400
  gemm32<false, false, false, false, false><<<dim3(4, 13, BATCH), 256, 0, stream>>>(
      xf, NN, NNODE, gcn1_w, 0, HID, nullptr, nullptr, 0,
      xw, (long)NNODE * HID, HID, NNODE, HID, NNODE);
  // G6: h = relu(An^T @ XW + gcn1_b)           (AT, batched B)
  gemm32<true, true, false, true, false><<<dim3(4, 13, BATCH), 256, 0, stream>>>(
      dl, NN, NNODE, xw, (long)NNODE * HID, HID, gcn1_b, nullptr, 0,
      hbuf, (long)NNODE * HID, HID, NNODE, HID, NNODE);
  // G7: t = h @ gcn2_w                         M=400 N=128 K=128 (into xw)
  gemm32<false, false, false, false, false><<<dim3(4, 13, BATCH), 256, 0, stream>>>(
      hbuf, (long)NNODE * HID, HID, gcn2_w, 0, HID, nullptr, nullptr, 0,
      xw, (long)NNODE * HID, HID, NNODE, HID, HID);
  // G8: h2 = An^T @ t + gcn2_b                 (AT, batched B, into hbuf)
  gemm32<true, true, false, false, false><<<dim3(4, 13, BATCH), 256, 0, stream>>>(
      dl, NN, NNODE, xw, (long)NNODE * HID, HID, gcn2_b, nullptr, 0,
      hbuf, (long)NNODE * HID, HID, NNODE, HID, NNODE);

  head_k<<<BATCH, HID, 0, stream>>>(hbuf, fc_w, fc_b, out);
}

// Round 5
// 1057.061 us; speedup vs baseline: 2.2742x; 1.6299x over previous
//
#include <hip/hip_runtime.h>
#include <math.h>

#define BATCH 128
#define NNODE 400
#define HID   128
#define NN    (NNODE*NNODE)      // 160000
#define KSEL  32000              // int(NN*0.2)
#define EQCAP 1024
#define EPSF  1e-9f
#define TSPLIT 8                 // histogram blocks per sample
#define SEG   (NN / TSPLIT)      // 20000 (divisible by 4)

// map float -> unsigned so that descending float order == descending unsigned order
__device__ __forceinline__ unsigned tokey(float f) {
  unsigned u = __float_as_uint(f);
  return (u & 0x80000000u) ? ~u : (u | 0x80000000u);
}

// ---------------------------------------------------------------------------
// 64x64-tile fp32 GEMM, 4x4 per-thread microkernel, float4 LDS fragments.
// C[m,n] = act( sum_k A[m,k]*B[k,n] + bias[n] + Res )
// AT: A stored transposed (A[k*lda+m]); TS: store transposed (C[n*ldc+m])
// Requires: K % 16 == 0, lda/ldb % 4 == 0 (true for all call sites: 400/128).
// ---------------------------------------------------------------------------
#define BK 16
#define LP 68   // LDS row pad: multiple of 4 (float4 align), spreads banks

template<bool AT, bool BIAS, bool RES, bool RELU, bool TS>
__global__ void __launch_bounds__(256) gemm64(
    const float* __restrict__ A, long sA, int lda,
    const float* __restrict__ B, long sB, int ldb,
    const float* __restrict__ bias,
    const float* __restrict__ Res, long sRes,
    float* __restrict__ C, long sC, int ldc,
    int M, int Nc, int K)
{
  __shared__ float As[BK][LP];
  __shared__ float Bs[BK][LP];
  const int bz = blockIdx.z;
  A += (size_t)bz * sA;
  B += (size_t)bz * sB;
  C += (size_t)bz * sC;
  const float* Rp = RES ? (Res + (size_t)bz * sRes) : nullptr;

  const int n0 = blockIdx.x * 64;
  const int m0 = blockIdx.y * 64;
  const int tid = threadIdx.x;
  const int tx = tid & 15, ty = tid >> 4;
  const bool edgeM = (m0 + 64 > M);
  const bool edgeN = (n0 + 64 > Nc);

  float acc[4][4];
#pragma unroll
  for (int i = 0; i < 4; ++i)
#pragma unroll
    for (int j = 0; j < 4; ++j) acc[i][j] = 0.f;

  for (int k0 = 0; k0 < K; k0 += BK) {
    // ---- stage A tile into As[kk][mm] ----
    if (!AT) {
      const int m = tid & 63, g = tid >> 6;           // g in 0..3 -> k group
      if (!edgeM) {
        const float4 v = *(const float4*)(A + (size_t)(m0 + m) * lda + k0 + 4 * g);
        As[4 * g + 0][m] = v.x; As[4 * g + 1][m] = v.y;
        As[4 * g + 2][m] = v.z; As[4 * g + 3][m] = v.w;
      } else {
        const int gm = m0 + m;
        const bool ok = gm < M;
#pragma unroll
        for (int j = 0; j < 4; ++j)
          As[4 * g + j][m] = ok ? A[(size_t)gm * lda + k0 + 4 * g + j] : 0.f;
      }
    } else {
      const int k = tid >> 4, mg = tid & 15;
      if (!edgeM) {
        const float4 v = *(const float4*)(A + (size_t)(k0 + k) * lda + m0 + 4 * mg);
        *(float4*)&As[k][4 * mg] = v;
      } else {
#pragma unroll
        for (int j = 0; j < 4; ++j) {
          const int gm = m0 + 4 * mg + j;
          As[k][4 * mg + j] = (gm < M) ? A[(size_t)(k0 + k) * lda + gm] : 0.f;
        }
      }
    }
    // ---- stage B tile into Bs[kk][nn] ----
    {
      const int k = tid >> 4, ng = tid & 15;
      if (!edgeN) {
        const float4 v = *(const float4*)(B + (size_t)(k0 + k) * ldb + n0 + 4 * ng);
        *(float4*)&Bs[k][4 * ng] = v;
      } else {
#pragma unroll
        for (int j = 0; j < 4; ++j) {
          const int gn = n0 + 4 * ng + j;
          Bs[k][4 * ng + j] = (gn < Nc) ? B[(size_t)(k0 + k) * ldb + gn] : 0.f;
        }
      }
    }
    __syncthreads();
#pragma unroll
    for (int kk = 0; kk < BK; ++kk) {
      const float4 a = *(const float4*)&As[kk][ty << 2];
      const float4 b = *(const float4*)&Bs[kk][tx << 2];
      const float av[4] = {a.x, a.y, a.z, a.w};
      const float bv[4] = {b.x, b.y, b.z, b.w};
#pragma unroll
      for (int i = 0; i < 4; ++i)
#pragma unroll
        for (int j = 0; j < 4; ++j) acc[i][j] += av[i] * bv[j];
    }
    __syncthreads();
  }

#pragma unroll
  for (int i = 0; i < 4; ++i) {
    const int m = m0 + (ty << 2) + i;
    if (m >= M) continue;
#pragma unroll
    for (int j = 0; j < 4; ++j) {
      const int n = n0 + (tx << 2) + j;
      if (n >= Nc) continue;
      float v = acc[i][j];
      if (BIAS) v += bias[n];
      const size_t loc = TS ? ((size_t)n * ldc + m) : ((size_t)m * ldc + n);
      if (RES) v += Rp[loc];
      if (RELU) v = fmaxf(v, 0.f);
      C[loc] = v;
    }
  }
}

// ---------------------------------------------------------------------------
__global__ void denom_k(const float* __restrict__ x, float* __restrict__ denom) {
  int b = threadIdx.x;
  if (b < BATCH) {
    float v = x[(size_t)b * NN];
    denom[b] = 0.5f * logf((1.0f + v + EPSF) / (1.0f - v + EPSF));
  }
}

__global__ void xf_k(const float* __restrict__ x, const float* __restrict__ denom,
                     float* __restrict__ xf) {
  size_t e = (size_t)blockIdx.x * 256 + threadIdx.x;
  if (e >= (size_t)BATCH * NN) return;
  int b = (int)(e / NN);
  float v = x[e];
  float t = 0.5f * logf((1.0f + v + EPSF) / (1.0f - v + EPSF));
  xf[e] = t / denom[b];
}

// x2 = xf + 0.5*(delta + delta^T) off-diagonal, in place over xf
__global__ void x2_k(float* __restrict__ xf, const float* __restrict__ dl) {
  size_t e = (size_t)blockIdx.x * 256 + threadIdx.x;
  if (e >= (size_t)BATCH * NN) return;
  int b = (int)(e / NN);
  int rem = (int)(e - (size_t)b * NN);
  int n = rem / NNODE, m = rem - n * NNODE;
  if (n == m) return;
  size_t base = (size_t)b * NN;
  float d = 0.5f * (dl[base + (size_t)n * NNODE + m] + dl[base + (size_t)m * NNODE + n]);
  xf[e] += d;
}

// ---------------------------------------------------------------------------
// Split top-k radix select. State: ghist[B][256], sprefix[B], sk[B].
// ---------------------------------------------------------------------------
__global__ void tz_init(unsigned* __restrict__ ghist, unsigned* __restrict__ sprefix,
                        int* __restrict__ sk, int* __restrict__ eqcnt) {
  int t = blockIdx.x * 256 + threadIdx.x;
  if (t < BATCH * 256) ghist[t] = 0u;
  if (t < BATCH) { sprefix[t] = 0u; sk[t] = KSEL; eqcnt[t] = 0; }
}

template<int PASS>
__global__ void __launch_bounds__(256) thist(const float* __restrict__ x2,
                                             const unsigned* __restrict__ sprefix,
                                             unsigned* __restrict__ ghist) {
  constexpr int shift = 24 - 8 * PASS;
  __shared__ unsigned h[8][256];   // 8 replicas to cut same-bin serialization
  const int b  = blockIdx.y;
  const int sb = blockIdx.x;
  const int tid = threadIdx.x;
  for (int i = tid; i < 8 * 256; i += 256) ((unsigned*)h)[i] = 0u;
  __syncthreads();

  const unsigned prefix = (PASS == 0) ? 0u : sprefix[b];
  const unsigned pmask  = (PASS == 0) ? 0u : (0xFFFFFFFFu << (shift + 8));
  const int rep = tid & 7;
  const float4* p4 = (const float4*)(x2 + (size_t)b * NN);
  const int i0 = sb * (SEG / 4), i1 = i0 + (SEG / 4);
  for (int i = i0 + tid; i < i1; i += 256) {
    float4 v = p4[i];
    unsigned k0 = tokey(v.x), k1 = tokey(v.y), k2 = tokey(v.z), k3 = tokey(v.w);
    if ((k0 & pmask) == prefix) atomicAdd(&h[rep][(k0 >> shift) & 255u], 1u);
    if ((k1 & pmask) == prefix) atomicAdd(&h[rep][(k1 >> shift) & 255u], 1u);
    if ((k2 & pmask) == prefix) atomicAdd(&h[rep][(k2 >> shift) & 255u], 1u);
    if ((k3 & pmask) == prefix) atomicAdd(&h[rep][(k3 >> shift) & 255u], 1u);
  }
  __syncthreads();
  if (tid < 256) {
    unsigned s = h[0][tid] + h[1][tid] + h[2][tid] + h[3][tid]
               + h[4][tid] + h[5][tid] + h[6][tid] + h[7][tid];
    if (s) atomicAdd(&ghist[b * 256 + tid], s);
  }
}

template<int PASS>
__global__ void __launch_bounds__(256) tpick(unsigned* __restrict__ ghist,
                                             unsigned* __restrict__ sprefix,
                                             int* __restrict__ sk,
                                             unsigned* __restrict__ tau,
                                             int* __restrict__ rrem) {
  constexpr int shift = 24 - 8 * PASS;
  const int b = blockIdx.x;
  __shared__ unsigned h[256];
  h[threadIdx.x] = ghist[b * 256 + threadIdx.x];
  __syncthreads();
  if (threadIdx.x == 0) {
    int k = sk[b];
    unsigned byte = 0u;
    for (int bin = 255; bin >= 0; --bin) {
      int c = (int)h[bin];
      if (c >= k) { byte = (unsigned)bin; break; }
      k -= c;
    }
    unsigned np = sprefix[b] | (byte << shift);
    sprefix[b] = np; sk[b] = k;
    if (PASS == 3) { tau[b] = np; rrem[b] = k; }
  }
  ghist[b * 256 + threadIdx.x] = 0u;   // ready for next pass
}

// A = x2 where key > tau, else 0; gather indices of exact ties
__global__ void build_k(const float* __restrict__ x2, const unsigned* __restrict__ tau,
                        float* __restrict__ A, int* __restrict__ eqcnt,
                        int* __restrict__ eqidx) {
  size_t e = (size_t)blockIdx.x * 256 + threadIdx.x;
  if (e >= (size_t)BATCH * NN) return;
  int b = (int)(e / NN);
  int i = (int)(e - (size_t)b * NN);
  float v = x2[e];
  unsigned key = tokey(v);
  unsigned tk = tau[b];
  A[e] = (key > tk) ? v : 0.f;
  if (key == tk) {
    int p = atomicAdd(&eqcnt[b], 1);
    if (p < EQCAP) eqidx[b * EQCAP + p] = i;
  }
}

// include the first rrem tie elements in ascending flat-index order
__global__ void eqfix_k(float* __restrict__ A, const float* __restrict__ x2,
                        const int* __restrict__ eqcnt, const int* __restrict__ eqidx,
                        const int* __restrict__ rrem) {
  int b = blockIdx.x;
  int cnt = eqcnt[b]; if (cnt > EQCAP) cnt = EQCAP;
  int r = rrem[b];
  for (int t = threadIdx.x; t < cnt; t += 256) {
    int idx = eqidx[b * EQCAP + t];
    int rank = 0;
    for (int u = 0; u < cnt; ++u) rank += (eqidx[b * EQCAP + u] < idx) ? 1 : 0;
    if (rank < r) A[(size_t)b * NN + idx] = x2[(size_t)b * NN + idx];
  }
}

__global__ void diag_k(float* __restrict__ A) {
  int t = blockIdx.x * blockDim.x + threadIdx.x;
  if (t >= BATCH * NNODE) return;
  int b = t / NNODE, i = t - b * NNODE;
  size_t o = (size_t)b * NN + (size_t)i * NNODE + i;
  if (A[o] == 0.f) A[o] = 1.0f;
}

__global__ void deg_k(const float* __restrict__ A, float* __restrict__ dinv) {
  int t = blockIdx.x * blockDim.x + threadIdx.x;
  if (t >= BATCH * NNODE) return;
  int b = t / NNODE, j = t - b * NNODE;
  const float* p = A + (size_t)b * NN + j;
  float s = 0.f;
  for (int i = 0; i < NNODE; ++i) s += p[(size_t)i * NNODE];
  dinv[t] = (s == 0.f) ? 0.f : 1.0f / sqrtf(s);
}

__global__ void an_k(float* __restrict__ A, const float* __restrict__ dinv) {
  size_t e = (size_t)blockIdx.x * 256 + threadIdx.x;
  if (e >= (size_t)BATCH * NN) return;
  int b = (int)(e / NN);
  int rem = (int)(e - (size_t)b * NN);
  int i = rem / NNODE, j = rem - i * NNODE;
  A[e] *= dinv[b * NNODE + i] * dinv[b * NNODE + j];
}

__global__ void head_k(const float* __restrict__ h2, const float* __restrict__ fc_w,
                       const float* __restrict__ fc_b, float* __restrict__ out) {
  int b = blockIdx.x;
  int f = threadIdx.x;  // 128
  float s = 0.f;
  const float* p = h2 + (size_t)b * NNODE * HID + f;
  for (int j = 0; j < NNODE; ++j) s += p[(size_t)j * HID];
  float pv = fmaxf(s / (float)NNODE, 0.f);
  __shared__ float r0[128], r1[128];
  r0[f] = pv * fc_w[f * 2 + 0];
  r1[f] = pv * fc_w[f * 2 + 1];
  __syncthreads();
  for (int sft = 64; sft > 0; sft >>= 1) {
    if (f < sft) { r0[f] += r0[f + sft]; r1[f] += r1[f + sft]; }
    __syncthreads();
  }
  if (f == 0) {
    out[b * 2 + 0] = r0[0] + fc_b[0];
    out[b * 2 + 1] = r1[0] + fc_b[1];
  }
}

// ---------------------------------------------------------------------------
extern "C" void kernel_launch(void* const* d_in, const int* in_sizes, int n_in,
                              void* d_out, int out_size, void* d_ws, size_t ws_size,
                              hipStream_t stream) {
  const float* x      = (const float*)d_in[0];
  // d_in[1] = slength (int32, unused by reference)
  const float* enc1_w = (const float*)d_in[2];
  const float* enc1_b = (const float*)d_in[3];
  const float* enc2_w = (const float*)d_in[4];
  const float* enc2_b = (const float*)d_in[5];
  const float* dec2_w = (const float*)d_in[6];
  const float* dec2_b = (const float*)d_in[7];
  const float* dec1_w = (const float*)d_in[8];
  const float* dec1_b = (const float*)d_in[9];
  const float* gcn1_w = (const float*)d_in[10];
  const float* gcn1_b = (const float*)d_in[11];
  const float* gcn2_w = (const float*)d_in[12];
  const float* gcn2_b = (const float*)d_in[13];
  const float* fc_w   = (const float*)d_in[14];
  const float* fc_b   = (const float*)d_in[15];
  float* out = (float*)d_out;
  (void)in_sizes; (void)n_in; (void)out_size; (void)ws_size;

  float* ws = (float*)d_ws;
  size_t off = 0;
  auto take = [&](size_t n) { float* p = ws + off; off += (n + 63) & ~(size_t)63; return p; };
  float* xf   = take((size_t)BATCH * NN);          // xf -> x2 (in place)
  float* dl   = take((size_t)BATCH * NN);          // delta -> A -> An (in place)
  float* o1   = take((size_t)BATCH * HID * NNODE); // out1 -> out2b (in place)
  float* o2   = take((size_t)BATCH * HID * HID);
  float* xw   = take((size_t)BATCH * NNODE * HID); // XW -> t (reused)
  float* hbuf = take((size_t)BATCH * NNODE * HID); // h -> h2 (reused)
  float* denom = take(BATCH);
  float* dinv  = take((size_t)BATCH * NNODE);
  unsigned* tau = (unsigned*)take(BATCH);
  int* rrem  = (int*)take(BATCH);
  int* eqcnt = (int*)take(BATCH);
  int* eqidx = (int*)take((size_t)BATCH * EQCAP);
  unsigned* ghist   = (unsigned*)take((size_t)BATCH * 256);
  unsigned* sprefix = (unsigned*)take(BATCH);
  int*      sk      = (int*)take(BATCH);

  const size_t TOT = (size_t)BATCH * NN;
  const int EW_BLK = (int)((TOT + 255) / 256);

  tz_init<<<128, 256, 0, stream>>>(ghist, sprefix, sk, eqcnt);
  denom_k<<<1, BATCH, 0, stream>>>(x, denom);
  xf_k<<<EW_BLK, 256, 0, stream>>>(x, denom, xf);

  // G1: out1[h,i] = relu(xf @ enc1_w + b)^T    M=400 N=128 K=400, trans-store
  gemm64<false, true, false, true, true><<<dim3(2, 7, BATCH), 256, 0, stream>>>(
      xf, NN, NNODE, enc1_w, 0, HID, enc1_b, nullptr, 0,
      o1, (long)HID * NNODE, NNODE, NNODE, HID, NNODE);
  // G2: out2 = relu(out1 @ enc2_w + b)         M=128 N=128 K=400
  gemm64<false, true, false, true, false><<<dim3(2, 2, BATCH), 256, 0, stream>>>(
      o1, (long)HID * NNODE, NNODE, enc2_w, 0, HID, enc2_b, nullptr, 0,
      o2, (long)HID * HID, HID, HID, HID, NNODE);
  // G3: out2b = relu(out2 @ dec2_w + b + out1) M=128 N=400 K=128, in-place into o1
  gemm64<false, true, true, true, false><<<dim3(7, 2, BATCH), 256, 0, stream>>>(
      o2, (long)HID * HID, HID, dec2_w, 0, NNODE, dec2_b,
      o1, (long)HID * NNODE,
      o1, (long)HID * NNODE, NNODE, HID, NNODE, HID);
  // G4: delta[n,m] = sum_h out2b[h,n]*dec1_w[h,m] + b   (AT)  M=400 N=400 K=128
  gemm64<true, true, false, false, false><<<dim3(7, 7, BATCH), 256, 0, stream>>>(
      o1, (long)HID * NNODE, NNODE, dec1_w, 0, NNODE, dec1_b, nullptr, 0,
      dl, NN, NNODE, NNODE, NNODE, HID);

  x2_k<<<EW_BLK, 256, 0, stream>>>(xf, dl);

  // split top-k radix select
  thist<0><<<dim3(TSPLIT, BATCH), 256, 0, stream>>>(xf, sprefix, ghist);
  tpick<0><<<BATCH, 256, 0, stream>>>(ghist, sprefix, sk, tau, rrem);
  thist<1><<<dim3(TSPLIT, BATCH), 256, 0, stream>>>(xf, sprefix, ghist);
  tpick<1><<<BATCH, 256, 0, stream>>>(ghist, sprefix, sk, tau, rrem);
  thist<2><<<dim3(TSPLIT, BATCH), 256, 0, stream>>>(xf, sprefix, ghist);
  tpick<2><<<BATCH, 256, 0, stream>>>(ghist, sprefix, sk, tau, rrem);
  thist<3><<<dim3(TSPLIT, BATCH), 256, 0, stream>>>(xf, sprefix, ghist);
  tpick<3><<<BATCH, 256, 0, stream>>>(ghist, sprefix, sk, tau, rrem);

  build_k<<<EW_BLK, 256, 0, stream>>>(xf, tau, dl, eqcnt, eqidx);
  eqfix_k<<<BATCH, 256, 0, stream>>>(dl, xf, eqcnt, eqidx, rrem);
  diag_k<<<(BATCH * NNODE + 255) / 256, 256, 0, stream>>>(dl);
  deg_k<<<(BATCH * NNODE + 255) / 256, 256, 0, stream>>>(dl, dinv);
  an_k<<<EW_BLK, 256, 0, stream>>>(dl, dinv);

  // G5: XW = x2 @ gcn1_w                       M=400 N=128 K=400
  gemm64<false, false, false, false, false><<<dim3(2, 7, BATCH), 256, 0, stream>>>(
      xf, NN, NNODE, gcn1_w, 0, HID, nullptr, nullptr, 0,
      xw, (long)NNODE * HID, HID, NNODE, HID, NNODE);
  // G6: h = relu(An^T @ XW + gcn1_b)           (AT, batched B)
  gemm64<true, true, false, true, false><<<dim3(2, 7, BATCH), 256, 0, stream>>>(
      dl, NN, NNODE, xw, (long)NNODE * HID, HID, gcn1_b, nullptr, 0,
      hbuf, (long)NNODE * HID, HID, NNODE, HID, NNODE);
  // G7: t = h @ gcn2_w                         M=400 N=128 K=128 (into xw)
  gemm64<false, false, false, false, false><<<dim3(2, 7, BATCH), 256, 0, stream>>>(
      hbuf, (long)NNODE * HID, HID, gcn2_w, 0, HID, nullptr, nullptr, 0,
      xw, (long)NNODE * HID, HID, NNODE, HID, HID);
  // G8: h2 = An^T @ t + gcn2_b                 (AT, batched B, into hbuf)
  gemm64<true, true, false, false, false><<<dim3(2, 7, BATCH), 256, 0, stream>>>(
      dl, NN, NNODE, xw, (long)NNODE * HID, HID, gcn2_b, nullptr, 0,
      hbuf, (long)NNODE * HID, HID, NNODE, HID, NNODE);

  head_k<<<BATCH, HID, 0, stream>>>(hbuf, fc_w, fc_b, out);
}

// Round 6
// 956.622 us; speedup vs baseline: 2.5130x; 1.1050x over previous
//
#include <hip/hip_runtime.h>
#include <math.h>

#define BATCH 128
#define NNODE 400
#define HID   128
#define NN    (NNODE*NNODE)      // 160000
#define KSEL  32000              // int(NN*0.2)
#define EQCAP 1024
#define EPSF  1e-9f
#define TSPLIT 8                 // histogram blocks per sample
#define SEG   (NN / TSPLIT)      // 20000 (divisible by 4)
#define NT    7                  // ceil(400/64)

// map float -> unsigned so that descending float order == descending unsigned order
__device__ __forceinline__ unsigned tokey(float f) {
  unsigned u = __float_as_uint(f);
  return (u & 0x80000000u) ? ~u : (u | 0x80000000u);
}

// ---------------------------------------------------------------------------
// 64x64-tile fp32 GEMM, 4x4 per-thread microkernel, float4 LDS fragments.
// C[m,n] = act( scl[m] * (sum_k A[m,k]*B[k,n]) + bias[n] + Res )
// AT: A stored transposed (A[k*lda+m]); TS: store transposed (C[n*ldc+m])
// SCL: multiply raw sum by scl[m] (pre-bias)
// Requires: K % 16 == 0, lda/ldb % 4 == 0 (true for all call sites: 400/128).
// ---------------------------------------------------------------------------
#define BK 16
#define LP 68   // LDS row pad: multiple of 4 (float4 align), spreads banks

template<bool AT, bool BIAS, bool RES, bool RELU, bool TS, bool SCL>
__global__ void __launch_bounds__(256) gemm64(
    const float* __restrict__ A, long sA, int lda,
    const float* __restrict__ B, long sB, int ldb,
    const float* __restrict__ bias,
    const float* __restrict__ Res, long sRes,
    const float* __restrict__ scl, long sScl,
    float* __restrict__ C, long sC, int ldc,
    int M, int Nc, int K)
{
  __shared__ float As[BK][LP];
  __shared__ float Bs[BK][LP];
  const int bz = blockIdx.z;
  A += (size_t)bz * sA;
  B += (size_t)bz * sB;
  C += (size_t)bz * sC;
  const float* Rp = RES ? (Res + (size_t)bz * sRes) : nullptr;
  const float* Sp = SCL ? (scl + (size_t)bz * sScl) : nullptr;

  const int n0 = blockIdx.x * 64;
  const int m0 = blockIdx.y * 64;
  const int tid = threadIdx.x;
  const int tx = tid & 15, ty = tid >> 4;
  const bool edgeM = (m0 + 64 > M);
  const bool edgeN = (n0 + 64 > Nc);

  float acc[4][4];
#pragma unroll
  for (int i = 0; i < 4; ++i)
#pragma unroll
    for (int j = 0; j < 4; ++j) acc[i][j] = 0.f;

  for (int k0 = 0; k0 < K; k0 += BK) {
    // ---- stage A tile into As[kk][mm] ----
    if (!AT) {
      const int m = tid & 63, g = tid >> 6;           // g in 0..3 -> k group
      if (!edgeM) {
        const float4 v = *(const float4*)(A + (size_t)(m0 + m) * lda + k0 + 4 * g);
        As[4 * g + 0][m] = v.x; As[4 * g + 1][m] = v.y;
        As[4 * g + 2][m] = v.z; As[4 * g + 3][m] = v.w;
      } else {
        const int gm = m0 + m;
        const bool ok = gm < M;
#pragma unroll
        for (int j = 0; j < 4; ++j)
          As[4 * g + j][m] = ok ? A[(size_t)gm * lda + k0 + 4 * g + j] : 0.f;
      }
    } else {
      const int k = tid >> 4, mg = tid & 15;
      if (!edgeM) {
        const float4 v = *(const float4*)(A + (size_t)(k0 + k) * lda + m0 + 4 * mg);
        *(float4*)&As[k][4 * mg] = v;
      } else {
#pragma unroll
        for (int j = 0; j < 4; ++j) {
          const int gm = m0 + 4 * mg + j;
          As[k][4 * mg + j] = (gm < M) ? A[(size_t)(k0 + k) * lda + gm] : 0.f;
        }
      }
    }
    // ---- stage B tile into Bs[kk][nn] ----
    {
      const int k = tid >> 4, ng = tid & 15;
      if (!edgeN) {
        const float4 v = *(const float4*)(B + (size_t)(k0 + k) * ldb + n0 + 4 * ng);
        *(float4*)&Bs[k][4 * ng] = v;
      } else {
#pragma unroll
        for (int j = 0; j < 4; ++j) {
          const int gn = n0 + 4 * ng + j;
          Bs[k][4 * ng + j] = (gn < Nc) ? B[(size_t)(k0 + k) * ldb + gn] : 0.f;
        }
      }
    }
    __syncthreads();
#pragma unroll
    for (int kk = 0; kk < BK; ++kk) {
      const float4 a = *(const float4*)&As[kk][ty << 2];
      const float4 b = *(const float4*)&Bs[kk][tx << 2];
      const float av[4] = {a.x, a.y, a.z, a.w};
      const float bv[4] = {b.x, b.y, b.z, b.w};
#pragma unroll
      for (int i = 0; i < 4; ++i)
#pragma unroll
        for (int j = 0; j < 4; ++j) acc[i][j] += av[i] * bv[j];
    }
    __syncthreads();
  }

#pragma unroll
  for (int i = 0; i < 4; ++i) {
    const int m = m0 + (ty << 2) + i;
    if (m >= M) continue;
#pragma unroll
    for (int j = 0; j < 4; ++j) {
      const int n = n0 + (tx << 2) + j;
      if (n >= Nc) continue;
      float v = acc[i][j];
      if (SCL) v *= Sp[m];
      if (BIAS) v += bias[n];
      const size_t loc = TS ? ((size_t)n * ldc + m) : ((size_t)m * ldc + n);
      if (RES) v += Rp[loc];
      if (RELU) v = fmaxf(v, 0.f);
      C[loc] = v;
    }
  }
}

// ---------------------------------------------------------------------------
// Fused G4 + symmetrize + x2 (+ top-k pass-0 histogram).
// Pair-tile grid over upper triangle: block computes delta[I,J] AND delta[J,I]
// from the same staged columns, forms x2 = xf + 0.5*(d+d^T) off-diag, writes
// both tiles in place over xf, and histograms the top byte of each element.
// ---------------------------------------------------------------------------
__global__ void __launch_bounds__(256) g4x2(
    const float* __restrict__ o1,   // [B][HID][NNODE]  (out2b, h-major)
    const float* __restrict__ w,    // dec1_w [HID][NNODE]
    const float* __restrict__ bias, // dec1_b [NNODE]
    float* __restrict__ xf,         // in-place -> x2, [B][NNODE][NNODE]
    unsigned* __restrict__ ghist)   // [B][256] pass-0 histogram
{
  __shared__ float smem[4 * BK * LP];   // staging: 4 tiles; epilogue: 64x65 transpose buf
  __shared__ unsigned hist[8][256];
  const int b = blockIdx.y;
  int p = blockIdx.x, bi = 0;
  while (p >= NT - bi) { p -= NT - bi; ++bi; }
  const int bj = bi + p;
  const int I0 = bi * 64, J0 = bj * 64;
  const bool diag = (bi == bj);
  const bool eI = (I0 + 64 > NNODE), eJ = (J0 + 64 > NNODE);

  o1 += (size_t)b * HID * NNODE;
  xf += (size_t)b * NN;
  unsigned* gh = ghist + b * 256;

  float (*AsI)[LP] = (float(*)[LP])smem;
  float (*AsJ)[LP] = (float(*)[LP])(smem + BK * LP);
  float (*WsI)[LP] = (float(*)[LP])(smem + 2 * BK * LP);
  float (*WsJ)[LP] = (float(*)[LP])(smem + 3 * BK * LP);

  const int tid = threadIdx.x;
  const int tx = tid & 15, ty = tid >> 4;
  for (int i = tid; i < 8 * 256; i += 256) ((unsigned*)hist)[i] = 0u;

  float acc1[4][4] = {{0.f}}, acc2[4][4] = {{0.f}};
#pragma unroll
  for (int i = 0; i < 4; ++i)
#pragma unroll
    for (int j = 0; j < 4; ++j) { acc1[i][j] = 0.f; acc2[i][j] = 0.f; }

  const int sk = tid >> 4, mg = tid & 15;   // staging coords
  for (int k0 = 0; k0 < HID; k0 += BK) {
    const float* ro = o1 + (size_t)(k0 + sk) * NNODE;
    const float* rw = w  + (size_t)(k0 + sk) * NNODE;
    if (!eI) {
      *(float4*)&AsI[sk][4 * mg] = *(const float4*)(ro + I0 + 4 * mg);
      *(float4*)&WsI[sk][4 * mg] = *(const float4*)(rw + I0 + 4 * mg);
    } else {
#pragma unroll
      for (int t = 0; t < 4; ++t) {
        const int c = I0 + 4 * mg + t; const bool ok = c < NNODE;
        AsI[sk][4 * mg + t] = ok ? ro[c] : 0.f;
        WsI[sk][4 * mg + t] = ok ? rw[c] : 0.f;
      }
    }
    if (!eJ) {
      *(float4*)&AsJ[sk][4 * mg] = *(const float4*)(ro + J0 + 4 * mg);
      *(float4*)&WsJ[sk][4 * mg] = *(const float4*)(rw + J0 + 4 * mg);
    } else {
#pragma unroll
      for (int t = 0; t < 4; ++t) {
        const int c = J0 + 4 * mg + t; const bool ok = c < NNODE;
        AsJ[sk][4 * mg + t] = ok ? ro[c] : 0.f;
        WsJ[sk][4 * mg + t] = ok ? rw[c] : 0.f;
      }
    }
    __syncthreads();
#pragma unroll
    for (int kk = 0; kk < BK; ++kk) {
      const float4 a1 = *(const float4*)&AsI[kk][ty << 2];
      const float4 b1 = *(const float4*)&WsJ[kk][tx << 2];
      const float4 a2 = *(const float4*)&AsJ[kk][tx << 2];
      const float4 b2 = *(const float4*)&WsI[kk][ty << 2];
      const float a1v[4] = {a1.x, a1.y, a1.z, a1.w}, b1v[4] = {b1.x, b1.y, b1.z, b1.w};
      const float a2v[4] = {a2.x, a2.y, a2.z, a2.w}, b2v[4] = {b2.x, b2.y, b2.z, b2.w};
#pragma unroll
      for (int i = 0; i < 4; ++i)
#pragma unroll
        for (int j = 0; j < 4; ++j) {
          acc1[i][j] += a1v[i] * b1v[j];   // delta[I0+ty4+i][J0+tx4+j]
          acc2[j][i] += a2v[j] * b2v[i];   // delta[J0+tx4+j][I0+ty4+i]
        }
    }
    __syncthreads();
  }

  // epilogue: x2 tile (I,J) in registers + histogram
  const int rep = tid & 7;
  float vvals[4][4];
  bool vok[4][4];
#pragma unroll
  for (int i = 0; i < 4; ++i) {
    const int n = I0 + (ty << 2) + i;
#pragma unroll
    for (int j = 0; j < 4; ++j) {
      const int m = J0 + (tx << 2) + j;
      const bool ok = (n < NNODE) && (m < NNODE);
      vok[i][j] = ok; vvals[i][j] = 0.f;
      if (ok) {
        float v = xf[(size_t)n * NNODE + m];
        if (n != m)
          v += 0.5f * (acc1[i][j] + acc2[j][i] + bias[m] + bias[n]);
        vvals[i][j] = v;
        atomicAdd(&hist[rep][tokey(v) >> 24], diag ? 1u : 2u);
      }
    }
  }
  // coalesced write of tile (I,J)
#pragma unroll
  for (int i = 0; i < 4; ++i) {
    const int n = I0 + (ty << 2) + i;
#pragma unroll
    for (int j = 0; j < 4; ++j) {
      const int m = J0 + (tx << 2) + j;
      if (vok[i][j]) xf[(size_t)n * NNODE + m] = vvals[i][j];
    }
  }
  // transpose write of tile (J,I) via LDS (x2 is bitwise symmetric)
  if (!diag) {
    __syncthreads();                      // staging arrays are free now
    float* Tb = smem;                     // 64 x 65
#pragma unroll
    for (int i = 0; i < 4; ++i)
#pragma unroll
      for (int j = 0; j < 4; ++j)
        Tb[((ty << 2) + i) * 65 + (tx << 2) + j] = vvals[i][j];
    __syncthreads();
#pragma unroll
    for (int i = 0; i < 4; ++i) {
      const int a = J0 + (ty << 2) + i;
      if (a >= NNODE) continue;
#pragma unroll
      for (int j = 0; j < 4; ++j) {
        const int c = I0 + (tx << 2) + j;
        if (c >= NNODE) continue;
        xf[(size_t)a * NNODE + c] = Tb[((tx << 2) + j) * 65 + (ty << 2) + i];
      }
    }
  }
  // flush pass-0 histogram
  __syncthreads();
  if (tid < 256) {
    const unsigned s = hist[0][tid] + hist[1][tid] + hist[2][tid] + hist[3][tid]
                     + hist[4][tid] + hist[5][tid] + hist[6][tid] + hist[7][tid];
    if (s) atomicAdd(&gh[tid], s);
  }
}

// ---------------------------------------------------------------------------
__global__ void denom_k(const float* __restrict__ x, float* __restrict__ denom) {
  int b = threadIdx.x;
  if (b < BATCH) {
    float v = x[(size_t)b * NN];
    denom[b] = 0.5f * logf((1.0f + v + EPSF) / (1.0f - v + EPSF));
  }
}

__global__ void xf_k(const float* __restrict__ x, const float* __restrict__ denom,
                     float* __restrict__ xf) {
  size_t e = (size_t)blockIdx.x * 256 + threadIdx.x;
  if (e >= (size_t)BATCH * NN) return;
  int b = (int)(e / NN);
  float v = x[e];
  float t = 0.5f * logf((1.0f + v + EPSF) / (1.0f - v + EPSF));
  xf[e] = t / denom[b];
}

// ---------------------------------------------------------------------------
// Split top-k radix select. State: ghist[B][256], sprefix[B], sk[B].
// ---------------------------------------------------------------------------
__global__ void tz_init(unsigned* __restrict__ ghist, unsigned* __restrict__ sprefix,
                        int* __restrict__ sk, int* __restrict__ eqcnt) {
  int t = blockIdx.x * 256 + threadIdx.x;
  if (t < BATCH * 256) ghist[t] = 0u;
  if (t < BATCH) { sprefix[t] = 0u; sk[t] = KSEL; eqcnt[t] = 0; }
}

template<int PASS>
__global__ void __launch_bounds__(256) thist(const float* __restrict__ x2,
                                             const unsigned* __restrict__ sprefix,
                                             unsigned* __restrict__ ghist) {
  constexpr int shift = 24 - 8 * PASS;
  __shared__ unsigned h[8][256];   // 8 replicas to cut same-bin serialization
  const int b  = blockIdx.y;
  const int sb = blockIdx.x;
  const int tid = threadIdx.x;
  for (int i = tid; i < 8 * 256; i += 256) ((unsigned*)h)[i] = 0u;
  __syncthreads();

  const unsigned prefix = sprefix[b];
  const unsigned pmask  = 0xFFFFFFFFu << (shift + 8);
  const int rep = tid & 7;
  const float4* p4 = (const float4*)(x2 + (size_t)b * NN);
  const int i0 = sb * (SEG / 4), i1 = i0 + (SEG / 4);
  for (int i = i0 + tid; i < i1; i += 256) {
    float4 v = p4[i];
    unsigned k0 = tokey(v.x), k1 = tokey(v.y), k2 = tokey(v.z), k3 = tokey(v.w);
    if ((k0 & pmask) == prefix) atomicAdd(&h[rep][(k0 >> shift) & 255u], 1u);
    if ((k1 & pmask) == prefix) atomicAdd(&h[rep][(k1 >> shift) & 255u], 1u);
    if ((k2 & pmask) == prefix) atomicAdd(&h[rep][(k2 >> shift) & 255u], 1u);
    if ((k3 & pmask) == prefix) atomicAdd(&h[rep][(k3 >> shift) & 255u], 1u);
  }
  __syncthreads();
  if (tid < 256) {
    unsigned s = h[0][tid] + h[1][tid] + h[2][tid] + h[3][tid]
               + h[4][tid] + h[5][tid] + h[6][tid] + h[7][tid];
    if (s) atomicAdd(&ghist[b * 256 + tid], s);
  }
}

template<int PASS>
__global__ void __launch_bounds__(256) tpick(unsigned* __restrict__ ghist,
                                             unsigned* __restrict__ sprefix,
                                             int* __restrict__ sk,
                                             unsigned* __restrict__ tau,
                                             int* __restrict__ rrem) {
  constexpr int shift = 24 - 8 * PASS;
  const int b = blockIdx.x;
  __shared__ unsigned h[256];
  h[threadIdx.x] = ghist[b * 256 + threadIdx.x];
  __syncthreads();
  if (threadIdx.x == 0) {
    int k = sk[b];
    unsigned byte = 0u;
    for (int bin = 255; bin >= 0; --bin) {
      int c = (int)h[bin];
      if (c >= k) { byte = (unsigned)bin; break; }
      k -= c;
    }
    unsigned np = sprefix[b] | (byte << shift);
    sprefix[b] = np; sk[b] = k;
    if (PASS == 3) { tau[b] = np; rrem[b] = k; }
  }
  ghist[b * 256 + threadIdx.x] = 0u;   // ready for next pass
}

// A = x2 where key > tau, else 0; gather indices of exact ties
__global__ void build_k(const float* __restrict__ x2, const unsigned* __restrict__ tau,
                        float* __restrict__ A, int* __restrict__ eqcnt,
                        int* __restrict__ eqidx) {
  size_t e = (size_t)blockIdx.x * 256 + threadIdx.x;
  if (e >= (size_t)BATCH * NN) return;
  int b = (int)(e / NN);
  int i = (int)(e - (size_t)b * NN);
  float v = x2[e];
  unsigned key = tokey(v);
  unsigned tk = tau[b];
  A[e] = (key > tk) ? v : 0.f;
  if (key == tk) {
    int p = atomicAdd(&eqcnt[b], 1);
    if (p < EQCAP) eqidx[b * EQCAP + p] = i;
  }
}

// include the first rrem tie elements in ascending flat-index order
__global__ void eqfix_k(float* __restrict__ A, const float* __restrict__ x2,
                        const int* __restrict__ eqcnt, const int* __restrict__ eqidx,
                        const int* __restrict__ rrem) {
  int b = blockIdx.x;
  int cnt = eqcnt[b]; if (cnt > EQCAP) cnt = EQCAP;
  int r = rrem[b];
  for (int t = threadIdx.x; t < cnt; t += 256) {
    int idx = eqidx[b * EQCAP + t];
    int rank = 0;
    for (int u = 0; u < cnt; ++u) rank += (eqidx[b * EQCAP + u] < idx) ? 1 : 0;
    if (rank < r) A[(size_t)b * NN + idx] = x2[(size_t)b * NN + idx];
  }
}

__global__ void diag_k(float* __restrict__ A) {
  int t = blockIdx.x * blockDim.x + threadIdx.x;
  if (t >= BATCH * NNODE) return;
  int b = t / NNODE, i = t - b * NNODE;
  size_t o = (size_t)b * NN + (size_t)i * NNODE + i;
  if (A[o] == 0.f) A[o] = 1.0f;
}

__global__ void deg_k(const float* __restrict__ A, float* __restrict__ dinv) {
  int t = blockIdx.x * blockDim.x + threadIdx.x;
  if (t >= BATCH * NNODE) return;
  int b = t / NNODE, j = t - b * NNODE;
  const float* p = A + (size_t)b * NN + j;
  float s = 0.f;
  for (int i = 0; i < NNODE; ++i) s += p[(size_t)i * NNODE];
  dinv[t] = (s == 0.f) ? 0.f : 1.0f / sqrtf(s);
}

__global__ void head_k(const float* __restrict__ h2, const float* __restrict__ fc_w,
                       const float* __restrict__ fc_b, float* __restrict__ out) {
  int b = blockIdx.x;
  int f = threadIdx.x;  // 128
  float s = 0.f;
  const float* p = h2 + (size_t)b * NNODE * HID + f;
  for (int j = 0; j < NNODE; ++j) s += p[(size_t)j * HID];
  float pv = fmaxf(s / (float)NNODE, 0.f);
  __shared__ float r0[128], r1[128];
  r0[f] = pv * fc_w[f * 2 + 0];
  r1[f] = pv * fc_w[f * 2 + 1];
  __syncthreads();
  for (int sft = 64; sft > 0; sft >>= 1) {
    if (f < sft) { r0[f] += r0[f + sft]; r1[f] += r1[f + sft]; }
    __syncthreads();
  }
  if (f == 0) {
    out[b * 2 + 0] = r0[0] + fc_b[0];
    out[b * 2 + 1] = r1[0] + fc_b[1];
  }
}

// ---------------------------------------------------------------------------
extern "C" void kernel_launch(void* const* d_in, const int* in_sizes, int n_in,
                              void* d_out, int out_size, void* d_ws, size_t ws_size,
                              hipStream_t stream) {
  const float* x      = (const float*)d_in[0];
  // d_in[1] = slength (int32, unused by reference)
  const float* enc1_w = (const float*)d_in[2];
  const float* enc1_b = (const float*)d_in[3];
  const float* enc2_w = (const float*)d_in[4];
  const float* enc2_b = (const float*)d_in[5];
  const float* dec2_w = (const float*)d_in[6];
  const float* dec2_b = (const float*)d_in[7];
  const float* dec1_w = (const float*)d_in[8];
  const float* dec1_b = (const float*)d_in[9];
  const float* gcn1_w = (const float*)d_in[10];
  const float* gcn1_b = (const float*)d_in[11];
  const float* gcn2_w = (const float*)d_in[12];
  const float* gcn2_b = (const float*)d_in[13];
  const float* fc_w   = (const float*)d_in[14];
  const float* fc_b   = (const float*)d_in[15];
  float* out = (float*)d_out;
  (void)in_sizes; (void)n_in; (void)out_size; (void)ws_size;

  float* ws = (float*)d_ws;
  size_t off = 0;
  auto take = [&](size_t n) { float* p = ws + off; off += (n + 63) & ~(size_t)63; return p; };
  float* xf   = take((size_t)BATCH * NN);          // xf -> x2 (in place)
  float* dl   = take((size_t)BATCH * NN);          // A (sparsified, unnormalized)
  float* o1   = take((size_t)BATCH * HID * NNODE); // out1 -> out2b (in place)
  float* o2   = take((size_t)BATCH * HID * HID);
  float* xw   = take((size_t)BATCH * NNODE * HID); // XW_scaled -> t_scaled (reused)
  float* hbuf = take((size_t)BATCH * NNODE * HID); // h -> h2 (reused)
  float* denom = take(BATCH);
  float* dinv  = take((size_t)BATCH * NNODE);
  unsigned* tau = (unsigned*)take(BATCH);
  int* rrem  = (int*)take(BATCH);
  int* eqcnt = (int*)take(BATCH);
  int* eqidx = (int*)take((size_t)BATCH * EQCAP);
  unsigned* ghist   = (unsigned*)take((size_t)BATCH * 256);
  unsigned* sprefix = (unsigned*)take(BATCH);
  int*      sk      = (int*)take(BATCH);

  const size_t TOT = (size_t)BATCH * NN;
  const int EW_BLK = (int)((TOT + 255) / 256);

  tz_init<<<128, 256, 0, stream>>>(ghist, sprefix, sk, eqcnt);
  denom_k<<<1, BATCH, 0, stream>>>(x, denom);
  xf_k<<<EW_BLK, 256, 0, stream>>>(x, denom, xf);

  // G1: out1[h,i] = relu(xf @ enc1_w + b)^T    M=400 N=128 K=400, trans-store
  gemm64<false, true, false, true, true, false><<<dim3(2, 7, BATCH), 256, 0, stream>>>(
      xf, NN, NNODE, enc1_w, 0, HID, enc1_b, nullptr, 0, nullptr, 0,
      o1, (long)HID * NNODE, NNODE, NNODE, HID, NNODE);
  // G2: out2 = relu(out1 @ enc2_w + b)         M=128 N=128 K=400
  gemm64<false, true, false, true, false, false><<<dim3(2, 2, BATCH), 256, 0, stream>>>(
      o1, (long)HID * NNODE, NNODE, enc2_w, 0, HID, enc2_b, nullptr, 0, nullptr, 0,
      o2, (long)HID * HID, HID, HID, HID, NNODE);
  // G3: out2b = relu(out2 @ dec2_w + b + out1) M=128 N=400 K=128, in-place into o1
  gemm64<false, true, true, true, false, false><<<dim3(7, 2, BATCH), 256, 0, stream>>>(
      o2, (long)HID * HID, HID, dec2_w, 0, NNODE, dec2_b,
      o1, (long)HID * NNODE, nullptr, 0,
      o1, (long)HID * NNODE, NNODE, HID, NNODE, HID);

  // G4 + symmetrize + x2 + top-k pass-0 histogram, fused (was gemm64 G4 + x2_k + thist<0>)
  g4x2<<<dim3(NT * (NT + 1) / 2, BATCH), 256, 0, stream>>>(o1, dec1_w, dec1_b, xf, ghist);

  // split top-k radix select (pass-0 histogram came from g4x2)
  tpick<0><<<BATCH, 256, 0, stream>>>(ghist, sprefix, sk, tau, rrem);
  thist<1><<<dim3(TSPLIT, BATCH), 256, 0, stream>>>(xf, sprefix, ghist);
  tpick<1><<<BATCH, 256, 0, stream>>>(ghist, sprefix, sk, tau, rrem);
  thist<2><<<dim3(TSPLIT, BATCH), 256, 0, stream>>>(xf, sprefix, ghist);
  tpick<2><<<BATCH, 256, 0, stream>>>(ghist, sprefix, sk, tau, rrem);
  thist<3><<<dim3(TSPLIT, BATCH), 256, 0, stream>>>(xf, sprefix, ghist);
  tpick<3><<<BATCH, 256, 0, stream>>>(ghist, sprefix, sk, tau, rrem);

  build_k<<<EW_BLK, 256, 0, stream>>>(xf, tau, dl, eqcnt, eqidx);
  eqfix_k<<<BATCH, 256, 0, stream>>>(dl, xf, eqcnt, eqidx, rrem);
  diag_k<<<(BATCH * NNODE + 255) / 256, 256, 0, stream>>>(dl);
  deg_k<<<(BATCH * NNODE + 255) / 256, 256, 0, stream>>>(dl, dinv);
  // an_k removed: dinv folded into G5-G8 epilogues (An never materialized)

  // G5: XWs[i,f] = dinv[i] * (x2 @ gcn1_w)[i,f]
  gemm64<false, false, false, false, false, true><<<dim3(2, 7, BATCH), 256, 0, stream>>>(
      xf, NN, NNODE, gcn1_w, 0, HID, nullptr, nullptr, 0, dinv, NNODE,
      xw, (long)NNODE * HID, HID, NNODE, HID, NNODE);
  // G6: h[j,f] = relu(dinv[j] * (A^T @ XWs)[j,f] + gcn1_b)
  gemm64<true, true, false, true, false, true><<<dim3(2, 7, BATCH), 256, 0, stream>>>(
      dl, NN, NNODE, xw, (long)NNODE * HID, HID, gcn1_b, nullptr, 0, dinv, NNODE,
      hbuf, (long)NNODE * HID, HID, NNODE, HID, NNODE);
  // G7: ts[i,f] = dinv[i] * (h @ gcn2_w)[i,f]  (into xw)
  gemm64<false, false, false, false, false, true><<<dim3(2, 7, BATCH), 256, 0, stream>>>(
      hbuf, (long)NNODE * HID, HID, gcn2_w, 0, HID, nullptr, nullptr, 0, dinv, NNODE,
      xw, (long)NNODE * HID, HID, NNODE, HID, HID);
  // G8: h2[j,f] = dinv[j] * (A^T @ ts)[j,f] + gcn2_b  (into hbuf)
  gemm64<true, true, false, false, false, true><<<dim3(2, 7, BATCH), 256, 0, stream>>>(
      dl, NN, NNODE, xw, (long)NNODE * HID, HID, gcn2_b, nullptr, 0, dinv, NNODE,
      hbuf, (long)NNODE * HID, HID, NNODE, HID, NNODE);

  head_k<<<BATCH, HID, 0, stream>>>(hbuf, fc_w, fc_b, out);
}

// Round 7
// 807.227 us; speedup vs baseline: 2.9781x; 1.1851x over previous
//
#include <hip/hip_runtime.h>
#include <hip/hip_bf16.h>
#include <math.h>

#define BATCH 128
#define NNODE 400
#define HID   128
#define NN    (NNODE*NNODE)      // 160000
#define KSEL  32000              // int(NN*0.2)
#define EQCAP 1024
#define EPSF  1e-9f
#define TSPLIT 8                 // histogram blocks per sample
#define SEG   (NN / TSPLIT)      // 20000 (divisible by 4)
#define NT    7                  // ceil(400/64)
#define KC400 14                 // ceil(400/32) padded to stage: 448/32
#define FRAGS (KC400*4096)       // shorts per plane for K=400-padded frag buffer

// map float -> unsigned so that descending float order == descending unsigned order
__device__ __forceinline__ unsigned tokey(float f) {
  unsigned u = __float_as_uint(f);
  return (u & 0x80000000u) ? ~u : (u | 0x80000000u);
}

// fp32 -> bf16 (RNE) and back, as raw shorts
__device__ __forceinline__ short f2bf(float f) {
  unsigned u = __float_as_uint(f);
  u += 0x7fffu + ((u >> 16) & 1u);
  return (short)(u >> 16);
}
__device__ __forceinline__ float bf2f(short s) {
  return __uint_as_float(((unsigned)(unsigned short)s) << 16);
}

typedef __attribute__((ext_vector_type(8))) short s8v;
typedef __attribute__((ext_vector_type(4))) short s4v;
typedef __attribute__((ext_vector_type(4))) float f4v;

// ---------------------------------------------------------------------------
// 64x64-tile fp32 GEMM (VALU), used for the precision-critical pre-top-k path.
// ---------------------------------------------------------------------------
#define BK 16
#define LP 68

template<bool AT, bool BIAS, bool RES, bool RELU, bool TS>
__global__ void __launch_bounds__(256) gemm64(
    const float* __restrict__ A, long sA, int lda,
    const float* __restrict__ B, long sB, int ldb,
    const float* __restrict__ bias,
    const float* __restrict__ Res, long sRes,
    float* __restrict__ C, long sC, int ldc,
    int M, int Nc, int K)
{
  __shared__ float As[BK][LP];
  __shared__ float Bs[BK][LP];
  const int bz = blockIdx.z;
  A += (size_t)bz * sA;
  B += (size_t)bz * sB;
  C += (size_t)bz * sC;
  const float* Rp = RES ? (Res + (size_t)bz * sRes) : nullptr;

  const int n0 = blockIdx.x * 64;
  const int m0 = blockIdx.y * 64;
  const int tid = threadIdx.x;
  const int tx = tid & 15, ty = tid >> 4;
  const bool edgeM = (m0 + 64 > M);
  const bool edgeN = (n0 + 64 > Nc);

  float acc[4][4];
#pragma unroll
  for (int i = 0; i < 4; ++i)
#pragma unroll
    for (int j = 0; j < 4; ++j) acc[i][j] = 0.f;

  for (int k0 = 0; k0 < K; k0 += BK) {
    if (!AT) {
      const int m = tid & 63, g = tid >> 6;
      if (!edgeM) {
        const float4 v = *(const float4*)(A + (size_t)(m0 + m) * lda + k0 + 4 * g);
        As[4 * g + 0][m] = v.x; As[4 * g + 1][m] = v.y;
        As[4 * g + 2][m] = v.z; As[4 * g + 3][m] = v.w;
      } else {
        const int gm = m0 + m;
        const bool ok = gm < M;
#pragma unroll
        for (int j = 0; j < 4; ++j)
          As[4 * g + j][m] = ok ? A[(size_t)gm * lda + k0 + 4 * g + j] : 0.f;
      }
    } else {
      const int k = tid >> 4, mg = tid & 15;
      if (!edgeM) {
        const float4 v = *(const float4*)(A + (size_t)(k0 + k) * lda + m0 + 4 * mg);
        *(float4*)&As[k][4 * mg] = v;
      } else {
#pragma unroll
        for (int j = 0; j < 4; ++j) {
          const int gm = m0 + 4 * mg + j;
          As[k][4 * mg + j] = (gm < M) ? A[(size_t)(k0 + k) * lda + gm] : 0.f;
        }
      }
    }
    {
      const int k = tid >> 4, ng = tid & 15;
      if (!edgeN) {
        const float4 v = *(const float4*)(B + (size_t)(k0 + k) * ldb + n0 + 4 * ng);
        *(float4*)&Bs[k][4 * ng] = v;
      } else {
#pragma unroll
        for (int j = 0; j < 4; ++j) {
          const int gn = n0 + 4 * ng + j;
          Bs[k][4 * ng + j] = (gn < Nc) ? B[(size_t)(k0 + k) * ldb + gn] : 0.f;
        }
      }
    }
    __syncthreads();
#pragma unroll
    for (int kk = 0; kk < BK; ++kk) {
      const float4 a = *(const float4*)&As[kk][ty << 2];
      const float4 b = *(const float4*)&Bs[kk][tx << 2];
      const float av[4] = {a.x, a.y, a.z, a.w};
      const float bv[4] = {b.x, b.y, b.z, b.w};
#pragma unroll
      for (int i = 0; i < 4; ++i)
#pragma unroll
        for (int j = 0; j < 4; ++j) acc[i][j] += av[i] * bv[j];
    }
    __syncthreads();
  }

#pragma unroll
  for (int i = 0; i < 4; ++i) {
    const int m = m0 + (ty << 2) + i;
    if (m >= M) continue;
#pragma unroll
    for (int j = 0; j < 4; ++j) {
      const int n = n0 + (tx << 2) + j;
      if (n >= Nc) continue;
      float v = acc[i][j];
      if (BIAS) v += bias[n];
      const size_t loc = TS ? ((size_t)n * ldc + m) : ((size_t)m * ldc + n);
      if (RES) v += Rp[loc];
      if (RELU) v = fmaxf(v, 0.f);
      C[loc] = v;
    }
  }
}

// ---------------------------------------------------------------------------
// Fused G4 + symmetrize + x2 (+ top-k pass-0 histogram). (unchanged from R6)
// ---------------------------------------------------------------------------
__global__ void __launch_bounds__(256) g4x2(
    const float* __restrict__ o1, const float* __restrict__ w,
    const float* __restrict__ bias, float* __restrict__ xf,
    unsigned* __restrict__ ghist)
{
  __shared__ float smem[4 * BK * LP];
  __shared__ unsigned hist[8][256];
  const int b = blockIdx.y;
  int p = blockIdx.x, bi = 0;
  while (p >= NT - bi) { p -= NT - bi; ++bi; }
  const int bj = bi + p;
  const int I0 = bi * 64, J0 = bj * 64;
  const bool diag = (bi == bj);
  const bool eI = (I0 + 64 > NNODE), eJ = (J0 + 64 > NNODE);

  o1 += (size_t)b * HID * NNODE;
  xf += (size_t)b * NN;
  unsigned* gh = ghist + b * 256;

  float (*AsI)[LP] = (float(*)[LP])smem;
  float (*AsJ)[LP] = (float(*)[LP])(smem + BK * LP);
  float (*WsI)[LP] = (float(*)[LP])(smem + 2 * BK * LP);
  float (*WsJ)[LP] = (float(*)[LP])(smem + 3 * BK * LP);

  const int tid = threadIdx.x;
  const int tx = tid & 15, ty = tid >> 4;
  for (int i = tid; i < 8 * 256; i += 256) ((unsigned*)hist)[i] = 0u;

  float acc1[4][4], acc2[4][4];
#pragma unroll
  for (int i = 0; i < 4; ++i)
#pragma unroll
    for (int j = 0; j < 4; ++j) { acc1[i][j] = 0.f; acc2[i][j] = 0.f; }

  const int sk = tid >> 4, mg = tid & 15;
  for (int k0 = 0; k0 < HID; k0 += BK) {
    const float* ro = o1 + (size_t)(k0 + sk) * NNODE;
    const float* rw = w  + (size_t)(k0 + sk) * NNODE;
    if (!eI) {
      *(float4*)&AsI[sk][4 * mg] = *(const float4*)(ro + I0 + 4 * mg);
      *(float4*)&WsI[sk][4 * mg] = *(const float4*)(rw + I0 + 4 * mg);
    } else {
#pragma unroll
      for (int t = 0; t < 4; ++t) {
        const int c = I0 + 4 * mg + t; const bool ok = c < NNODE;
        AsI[sk][4 * mg + t] = ok ? ro[c] : 0.f;
        WsI[sk][4 * mg + t] = ok ? rw[c] : 0.f;
      }
    }
    if (!eJ) {
      *(float4*)&AsJ[sk][4 * mg] = *(const float4*)(ro + J0 + 4 * mg);
      *(float4*)&WsJ[sk][4 * mg] = *(const float4*)(rw + J0 + 4 * mg);
    } else {
#pragma unroll
      for (int t = 0; t < 4; ++t) {
        const int c = J0 + 4 * mg + t; const bool ok = c < NNODE;
        AsJ[sk][4 * mg + t] = ok ? ro[c] : 0.f;
        WsJ[sk][4 * mg + t] = ok ? rw[c] : 0.f;
      }
    }
    __syncthreads();
#pragma unroll
    for (int kk = 0; kk < BK; ++kk) {
      const float4 a1 = *(const float4*)&AsI[kk][ty << 2];
      const float4 b1 = *(const float4*)&WsJ[kk][tx << 2];
      const float4 a2 = *(const float4*)&AsJ[kk][tx << 2];
      const float4 b2 = *(const float4*)&WsI[kk][ty << 2];
      const float a1v[4] = {a1.x, a1.y, a1.z, a1.w}, b1v[4] = {b1.x, b1.y, b1.z, b1.w};
      const float a2v[4] = {a2.x, a2.y, a2.z, a2.w}, b2v[4] = {b2.x, b2.y, b2.z, b2.w};
#pragma unroll
      for (int i = 0; i < 4; ++i)
#pragma unroll
        for (int j = 0; j < 4; ++j) {
          acc1[i][j] += a1v[i] * b1v[j];
          acc2[j][i] += a2v[j] * b2v[i];
        }
    }
    __syncthreads();
  }

  const int rep = tid & 7;
  float vvals[4][4];
  bool vok[4][4];
#pragma unroll
  for (int i = 0; i < 4; ++i) {
    const int n = I0 + (ty << 2) + i;
#pragma unroll
    for (int j = 0; j < 4; ++j) {
      const int m = J0 + (tx << 2) + j;
      const bool ok = (n < NNODE) && (m < NNODE);
      vok[i][j] = ok; vvals[i][j] = 0.f;
      if (ok) {
        float v = xf[(size_t)n * NNODE + m];
        if (n != m)
          v += 0.5f * (acc1[i][j] + acc2[j][i] + bias[m] + bias[n]);
        vvals[i][j] = v;
        atomicAdd(&hist[rep][tokey(v) >> 24], diag ? 1u : 2u);
      }
    }
  }
#pragma unroll
  for (int i = 0; i < 4; ++i) {
    const int n = I0 + (ty << 2) + i;
#pragma unroll
    for (int j = 0; j < 4; ++j) {
      const int m = J0 + (tx << 2) + j;
      if (vok[i][j]) xf[(size_t)n * NNODE + m] = vvals[i][j];
    }
  }
  if (!diag) {
    __syncthreads();
    float* Tb = smem;
#pragma unroll
    for (int i = 0; i < 4; ++i)
#pragma unroll
      for (int j = 0; j < 4; ++j)
        Tb[((ty << 2) + i) * 65 + (tx << 2) + j] = vvals[i][j];
    __syncthreads();
#pragma unroll
    for (int i = 0; i < 4; ++i) {
      const int a = J0 + (ty << 2) + i;
      if (a >= NNODE) continue;
#pragma unroll
      for (int j = 0; j < 4; ++j) {
        const int c = I0 + (tx << 2) + j;
        if (c >= NNODE) continue;
        xf[(size_t)a * NNODE + c] = Tb[((tx << 2) + j) * 65 + (ty << 2) + i];
      }
    }
  }
  __syncthreads();
  if (tid < 256) {
    const unsigned s = hist[0][tid] + hist[1][tid] + hist[2][tid] + hist[3][tid]
                     + hist[4][tid] + hist[5][tid] + hist[6][tid] + hist[7][tid];
    if (s) atomicAdd(&gh[tid], s);
  }
}

// ---------------------------------------------------------------------------
// bsplit: W[K][128] fp32 -> MFMA-fragment-ordered bf16 hi/lo planes.
// frag index: [kchunk][ntile][lane=quad*16+(n&15)][j=k&7], plane stride KC*4096.
// ---------------------------------------------------------------------------
__global__ void bsplit(const float* __restrict__ W, int K, int Kpad,
                       short* __restrict__ out) {
  int t = blockIdx.x * 256 + threadIdx.x;
  if (t >= Kpad * 128) return;
  int k = t >> 7, n = t & 127;
  float v = (k < K) ? W[(size_t)k * 128 + n] : 0.f;
  short hi = f2bf(v);
  short lo = f2bf(v - bf2f(hi));
  size_t idx = (((size_t)(k >> 5) * 8 + (n >> 4)) * 64
                + (((k >> 3) & 3) * 16 + (n & 15))) * 8 + (k & 7);
  out[idx] = hi;
  out[(size_t)(Kpad >> 5) * 4096 + idx] = lo;
}

// ---------------------------------------------------------------------------
// MFMA GEMM (bf16 split-3): C[m,n] = act(scl[m]*sum_k A[m,k]*B[k,n] + bias[n])
// N fixed 128. A fp32 (AT: A[m,k]=Araw[k*lda+m]); B pre-split frag bf16 global.
// FRAG: write output as frag-ordered bf16 hi/lo (for use as next B), rows
// m>=M written as zeros (frag buffer fully initialized up to 64*gridDim.y rows).
// ---------------------------------------------------------------------------
template<bool AT, bool FRAG, bool BIAS, bool RELU>
__global__ void __launch_bounds__(256) mfgemm(
    const float* __restrict__ A, long sA, int lda,
    const short* __restrict__ Bf, long sB, int kc,     // B plane stride kc*4096
    const float* __restrict__ bias,
    const float* __restrict__ scl,                     // dinv, stride NNODE
    float* __restrict__ Cf, long sCf,
    short* __restrict__ Cfrag, long sCfrag, int okc,   // out plane stride okc*4096
    int M, int K)
{
  __shared__ float As[64][68];
  const int bz = blockIdx.y;
  A += (size_t)bz * sA;
  Bf += (size_t)bz * sB;
  scl += (size_t)bz * NNODE;
  if (!FRAG) Cf += (size_t)bz * sCf;
  else       Cfrag += (size_t)bz * sCfrag;

  const int tid = threadIdx.x;
  const int lane = tid & 63, wave = tid >> 6;
  const int wqm = wave >> 1, wqn = wave & 1;
  const int quad = lane >> 4, l15 = lane & 15;
  const int m0 = blockIdx.x * 64;

  f4v acc[2][4];
#pragma unroll
  for (int i = 0; i < 2; ++i)
#pragma unroll
    for (int j = 0; j < 4; ++j) acc[i][j] = (f4v){0.f, 0.f, 0.f, 0.f};

  const int nstage = (K + 63) >> 6;
  for (int st = 0; st < nstage; ++st) {
    const int k0 = st << 6;
    if (st) __syncthreads();
    // ---- stage A [64m][64k] fp32 ----
    if (!AT) {
      const int mrow = tid >> 4;
      const int k4 = (tid & 15) << 2;
#pragma unroll
      for (int u = 0; u < 4; ++u) {
        const int m = mrow + (u << 4);
        const int gm = m0 + m, gk = k0 + k4;
        float4 v = {0.f, 0.f, 0.f, 0.f};
        if (gm < M) {
          if (gk + 4 <= K) v = *(const float4*)(A + (size_t)gm * lda + gk);
          else {
            float* pv = (float*)&v;
#pragma unroll
            for (int j = 0; j < 4; ++j)
              if (gk + j < K) pv[j] = A[(size_t)gm * lda + gk + j];
          }
        }
        *(float4*)&As[m][k4] = v;
      }
    } else {
      const int kk = tid >> 4;
      const int m4 = (tid & 15) << 2;
#pragma unroll
      for (int u = 0; u < 4; ++u) {
        const int gk = k0 + kk + (u << 4);
        float4 v = {0.f, 0.f, 0.f, 0.f};
        if (gk < K) {
          if (m0 + m4 + 4 <= M) v = *(const float4*)(A + (size_t)gk * lda + m0 + m4);
          else {
            float* pv = (float*)&v;
#pragma unroll
            for (int j = 0; j < 4; ++j)
              if (m0 + m4 + j < M) pv[j] = A[(size_t)gk * lda + m0 + m4 + j];
          }
        }
        As[m4 + 0][kk + (u << 4)] = v.x;
        As[m4 + 1][kk + (u << 4)] = v.y;
        As[m4 + 2][kk + (u << 4)] = v.z;
        As[m4 + 3][kk + (u << 4)] = v.w;
      }
    }
    __syncthreads();

#pragma unroll
    for (int c2 = 0; c2 < 2; ++c2) {
      const int c = (st << 1) + c2;
      // B fragments (hi/lo) straight from global, coalesced 16B/lane
      s8v bhi[4], blo[4];
#pragma unroll
      for (int nt = 0; nt < 4; ++nt) {
        const int ntg = (wqn << 2) + nt;
        const size_t off = (((size_t)c * 8 + ntg) * 64 + lane) * 8;
        bhi[nt] = *(const s8v*)(Bf + off);
        blo[nt] = *(const s8v*)(Bf + (size_t)kc * 4096 + off);
      }
      // A fragments: read fp32 from LDS, split to hi/lo bf16
#pragma unroll
      for (int mt = 0; mt < 2; ++mt) {
        const int row = (wqm << 5) + (mt << 4) + l15;
        const int kof = (c2 << 5) + (quad << 3);
        const f4v a0 = *(const f4v*)&As[row][kof];
        const f4v a1 = *(const f4v*)&As[row][kof + 4];
        s8v ah, al;
#pragma unroll
        for (int j = 0; j < 4; ++j) {
          short h0 = f2bf(a0[j]); ah[j] = h0; al[j] = f2bf(a0[j] - bf2f(h0));
          short h1 = f2bf(a1[j]); ah[j + 4] = h1; al[j + 4] = f2bf(a1[j] - bf2f(h1));
        }
#pragma unroll
        for (int nt = 0; nt < 4; ++nt) {
          acc[mt][nt] = __builtin_amdgcn_mfma_f32_16x16x32_bf16(ah, bhi[nt], acc[mt][nt], 0, 0, 0);
          acc[mt][nt] = __builtin_amdgcn_mfma_f32_16x16x32_bf16(ah, blo[nt], acc[mt][nt], 0, 0, 0);
          acc[mt][nt] = __builtin_amdgcn_mfma_f32_16x16x32_bf16(al, bhi[nt], acc[mt][nt], 0, 0, 0);
        }
      }
    }
  }

  // ---- epilogue ----
#pragma unroll
  for (int mt = 0; mt < 2; ++mt) {
    const int mb = m0 + (wqm << 5) + (mt << 4) + (quad << 2);
#pragma unroll
    for (int nt = 0; nt < 4; ++nt) {
      const int n = (wqn << 6) + (nt << 4) + l15;
      const f4v a = acc[mt][nt];
      if (!FRAG) {
#pragma unroll
        for (int reg = 0; reg < 4; ++reg) {
          const int m = mb + reg;
          if (m < M) {
            float v = a[reg] * scl[m];
            if (BIAS) v += bias[n];
            if (RELU) v = fmaxf(v, 0.f);
            Cf[(size_t)m * 128 + n] = v;
          }
        }
      } else {
        s4v h4, l4;
#pragma unroll
        for (int reg = 0; reg < 4; ++reg) {
          const int m = mb + reg;
          float v = (m < M) ? a[reg] * scl[m] : 0.f;
          short hh = f2bf(v);
          h4[reg] = hh; l4[reg] = f2bf(v - bf2f(hh));
        }
        const int chunkT = mb >> 5, quadT = (mb >> 3) & 3, jT0 = mb & 7;
        const size_t off = (((size_t)chunkT * 8 + (wqn << 2) + nt) * 64
                            + quadT * 16 + l15) * 8 + jT0;
        *(s4v*)(Cfrag + off) = h4;
        *(s4v*)(Cfrag + (size_t)okc * 4096 + off) = l4;
      }
    }
  }
}

// ---------------------------------------------------------------------------
__global__ void denom_k(const float* __restrict__ x, float* __restrict__ denom) {
  int b = threadIdx.x;
  if (b < BATCH) {
    float v = x[(size_t)b * NN];
    denom[b] = 0.5f * logf((1.0f + v + EPSF) / (1.0f - v + EPSF));
  }
}

__global__ void xf_k(const float* __restrict__ x, const float* __restrict__ denom,
                     float* __restrict__ xf) {
  size_t e = (size_t)blockIdx.x * 256 + threadIdx.x;
  if (e >= (size_t)BATCH * NN) return;
  int b = (int)(e / NN);
  float v = x[e];
  float t = 0.5f * logf((1.0f + v + EPSF) / (1.0f - v + EPSF));
  xf[e] = t / denom[b];
}

// ---------------------------------------------------------------------------
__global__ void tz_init(unsigned* __restrict__ ghist, unsigned* __restrict__ sprefix,
                        int* __restrict__ sk, int* __restrict__ eqcnt) {
  int t = blockIdx.x * 256 + threadIdx.x;
  if (t < BATCH * 256) ghist[t] = 0u;
  if (t < BATCH) { sprefix[t] = 0u; sk[t] = KSEL; eqcnt[t] = 0; }
}

template<int PASS>
__global__ void __launch_bounds__(256) thist(const float* __restrict__ x2,
                                             const unsigned* __restrict__ sprefix,
                                             unsigned* __restrict__ ghist) {
  constexpr int shift = 24 - 8 * PASS;
  __shared__ unsigned h[8][256];
  const int b  = blockIdx.y;
  const int sb = blockIdx.x;
  const int tid = threadIdx.x;
  for (int i = tid; i < 8 * 256; i += 256) ((unsigned*)h)[i] = 0u;
  __syncthreads();

  const unsigned prefix = sprefix[b];
  const unsigned pmask  = 0xFFFFFFFFu << (shift + 8);
  const int rep = tid & 7;
  const float4* p4 = (const float4*)(x2 + (size_t)b * NN);
  const int i0 = sb * (SEG / 4), i1 = i0 + (SEG / 4);
  for (int i = i0 + tid; i < i1; i += 256) {
    float4 v = p4[i];
    unsigned k0 = tokey(v.x), k1 = tokey(v.y), k2 = tokey(v.z), k3 = tokey(v.w);
    if ((k0 & pmask) == prefix) atomicAdd(&h[rep][(k0 >> shift) & 255u], 1u);
    if ((k1 & pmask) == prefix) atomicAdd(&h[rep][(k1 >> shift) & 255u], 1u);
    if ((k2 & pmask) == prefix) atomicAdd(&h[rep][(k2 >> shift) & 255u], 1u);
    if ((k3 & pmask) == prefix) atomicAdd(&h[rep][(k3 >> shift) & 255u], 1u);
  }
  __syncthreads();
  if (tid < 256) {
    unsigned s = h[0][tid] + h[1][tid] + h[2][tid] + h[3][tid]
               + h[4][tid] + h[5][tid] + h[6][tid] + h[7][tid];
    if (s) atomicAdd(&ghist[b * 256 + tid], s);
  }
}

template<int PASS>
__global__ void __launch_bounds__(256) tpick(unsigned* __restrict__ ghist,
                                             unsigned* __restrict__ sprefix,
                                             int* __restrict__ sk,
                                             unsigned* __restrict__ tau,
                                             int* __restrict__ rrem) {
  constexpr int shift = 24 - 8 * PASS;
  const int b = blockIdx.x;
  __shared__ unsigned h[256];
  h[threadIdx.x] = ghist[b * 256 + threadIdx.x];
  __syncthreads();
  if (threadIdx.x == 0) {
    int k = sk[b];
    unsigned byte = 0u;
    for (int bin = 255; bin >= 0; --bin) {
      int c = (int)h[bin];
      if (c >= k) { byte = (unsigned)bin; break; }
      k -= c;
    }
    unsigned np = sprefix[b] | (byte << shift);
    sprefix[b] = np; sk[b] = k;
    if (PASS == 3) { tau[b] = np; rrem[b] = k; }
  }
  ghist[b * 256 + threadIdx.x] = 0u;
}

__global__ void build_k(const float* __restrict__ x2, const unsigned* __restrict__ tau,
                        float* __restrict__ A, int* __restrict__ eqcnt,
                        int* __restrict__ eqidx) {
  size_t e = (size_t)blockIdx.x * 256 + threadIdx.x;
  if (e >= (size_t)BATCH * NN) return;
  int b = (int)(e / NN);
  int i = (int)(e - (size_t)b * NN);
  float v = x2[e];
  unsigned key = tokey(v);
  unsigned tk = tau[b];
  A[e] = (key > tk) ? v : 0.f;
  if (key == tk) {
    int p = atomicAdd(&eqcnt[b], 1);
    if (p < EQCAP) eqidx[b * EQCAP + p] = i;
  }
}

__global__ void eqfix_k(float* __restrict__ A, const float* __restrict__ x2,
                        const int* __restrict__ eqcnt, const int* __restrict__ eqidx,
                        const int* __restrict__ rrem) {
  int b = blockIdx.x;
  int cnt = eqcnt[b]; if (cnt > EQCAP) cnt = EQCAP;
  int r = rrem[b];
  for (int t = threadIdx.x; t < cnt; t += 256) {
    int idx = eqidx[b * EQCAP + t];
    int rank = 0;
    for (int u = 0; u < cnt; ++u) rank += (eqidx[b * EQCAP + u] < idx) ? 1 : 0;
    if (rank < r) A[(size_t)b * NN + idx] = x2[(size_t)b * NN + idx];
  }
}

__global__ void diag_k(float* __restrict__ A) {
  int t = blockIdx.x * blockDim.x + threadIdx.x;
  if (t >= BATCH * NNODE) return;
  int b = t / NNODE, i = t - b * NNODE;
  size_t o = (size_t)b * NN + (size_t)i * NNODE + i;
  if (A[o] == 0.f) A[o] = 1.0f;
}

__global__ void deg_k(const float* __restrict__ A, float* __restrict__ dinv) {
  int t = blockIdx.x * blockDim.x + threadIdx.x;
  if (t >= BATCH * NNODE) return;
  int b = t / NNODE, j = t - b * NNODE;
  const float* p = A + (size_t)b * NN + j;
  float s = 0.f;
  for (int i = 0; i < NNODE; ++i) s += p[(size_t)i * NNODE];
  dinv[t] = (s == 0.f) ? 0.f : 1.0f / sqrtf(s);
}

__global__ void head_k(const float* __restrict__ h2, const float* __restrict__ fc_w,
                       const float* __restrict__ fc_b, float* __restrict__ out) {
  int b = blockIdx.x;
  int f = threadIdx.x;
  float s = 0.f;
  const float* p = h2 + (size_t)b * NNODE * HID + f;
  for (int j = 0; j < NNODE; ++j) s += p[(size_t)j * HID];
  float pv = fmaxf(s / (float)NNODE, 0.f);
  __shared__ float r0[128], r1[128];
  r0[f] = pv * fc_w[f * 2 + 0];
  r1[f] = pv * fc_w[f * 2 + 1];
  __syncthreads();
  for (int sft = 64; sft > 0; sft >>= 1) {
    if (f < sft) { r0[f] += r0[f + sft]; r1[f] += r1[f + sft]; }
    __syncthreads();
  }
  if (f == 0) {
    out[b * 2 + 0] = r0[0] + fc_b[0];
    out[b * 2 + 1] = r1[0] + fc_b[1];
  }
}

// ---------------------------------------------------------------------------
extern "C" void kernel_launch(void* const* d_in, const int* in_sizes, int n_in,
                              void* d_out, int out_size, void* d_ws, size_t ws_size,
                              hipStream_t stream) {
  const float* x      = (const float*)d_in[0];
  const float* enc1_w = (const float*)d_in[2];
  const float* enc1_b = (const float*)d_in[3];
  const float* enc2_w = (const float*)d_in[4];
  const float* enc2_b = (const float*)d_in[5];
  const float* dec2_w = (const float*)d_in[6];
  const float* dec2_b = (const float*)d_in[7];
  const float* dec1_w = (const float*)d_in[8];
  const float* dec1_b = (const float*)d_in[9];
  const float* gcn1_w = (const float*)d_in[10];
  const float* gcn1_b = (const float*)d_in[11];
  const float* gcn2_w = (const float*)d_in[12];
  const float* gcn2_b = (const float*)d_in[13];
  const float* fc_w   = (const float*)d_in[14];
  const float* fc_b   = (const float*)d_in[15];
  float* out = (float*)d_out;
  (void)in_sizes; (void)n_in; (void)out_size; (void)ws_size;

  float* ws = (float*)d_ws;
  size_t off = 0;
  auto take = [&](size_t n) { float* p = ws + off; off += (n + 63) & ~(size_t)63; return p; };
  float* xf   = take((size_t)BATCH * NN);          // xf -> x2 (in place)
  float* dl   = take((size_t)BATCH * NN);          // A (sparsified, unnormalized)
  float* o1   = take((size_t)BATCH * HID * NNODE); // out1 -> out2b; later xwfrag alias
  float* o2   = take((size_t)BATCH * HID * HID);   // (xwfrag spills into o2 region)
  float* hbuf = take((size_t)BATCH * NNODE * HID); // h -> h2
  float* denom = take(BATCH);
  float* dinv  = take((size_t)BATCH * NNODE);
  unsigned* tau = (unsigned*)take(BATCH);
  int* rrem  = (int*)take(BATCH);
  int* eqcnt = (int*)take(BATCH);
  int* eqidx = (int*)take((size_t)BATCH * EQCAP);
  unsigned* ghist   = (unsigned*)take((size_t)BATCH * 256);
  unsigned* sprefix = (unsigned*)take(BATCH);
  int*      sk      = (int*)take(BATCH);
  short* w1frag = (short*)take((size_t)2 * FRAGS / 2 + 64);        // 2 planes, K=400pad
  short* w2frag = (short*)take((size_t)2 * 4 * 4096 / 2 + 64);     // 2 planes, K=128
  // xwfrag (per-sample 2*FRAGS shorts) aliases the dead o1+o2 region after g4x2
  short* xwfrag = (short*)o1;
  const long sXW = 2L * FRAGS;   // shorts per sample

  const size_t TOT = (size_t)BATCH * NN;
  const int EW_BLK = (int)((TOT + 255) / 256);

  tz_init<<<128, 256, 0, stream>>>(ghist, sprefix, sk, eqcnt);
  denom_k<<<1, BATCH, 0, stream>>>(x, denom);
  xf_k<<<EW_BLK, 256, 0, stream>>>(x, denom, xf);
  bsplit<<<(448 * 128 + 255) / 256, 256, 0, stream>>>(gcn1_w, NNODE, 448, w1frag);
  bsplit<<<(128 * 128 + 255) / 256, 256, 0, stream>>>(gcn2_w, HID, 128, w2frag);

  // G1: out1[h,i] = relu(xf @ enc1_w + b)^T    (fp32, pre-top-k)
  gemm64<false, true, false, true, true><<<dim3(2, 7, BATCH), 256, 0, stream>>>(
      xf, NN, NNODE, enc1_w, 0, HID, enc1_b, nullptr, 0,
      o1, (long)HID * NNODE, NNODE, NNODE, HID, NNODE);
  // G2
  gemm64<false, true, false, true, false><<<dim3(2, 2, BATCH), 256, 0, stream>>>(
      o1, (long)HID * NNODE, NNODE, enc2_w, 0, HID, enc2_b, nullptr, 0,
      o2, (long)HID * HID, HID, HID, HID, NNODE);
  // G3
  gemm64<false, true, true, true, false><<<dim3(7, 2, BATCH), 256, 0, stream>>>(
      o2, (long)HID * HID, HID, dec2_w, 0, NNODE, dec2_b,
      o1, (long)HID * NNODE, o1, (long)HID * NNODE, NNODE, HID, NNODE, HID);

  // G4 + symmetrize + x2 + top-k pass-0 histogram (fp32, pre-top-k)
  g4x2<<<dim3(NT * (NT + 1) / 2, BATCH), 256, 0, stream>>>(o1, dec1_w, dec1_b, xf, ghist);

  tpick<0><<<BATCH, 256, 0, stream>>>(ghist, sprefix, sk, tau, rrem);
  thist<1><<<dim3(TSPLIT, BATCH), 256, 0, stream>>>(xf, sprefix, ghist);
  tpick<1><<<BATCH, 256, 0, stream>>>(ghist, sprefix, sk, tau, rrem);
  thist<2><<<dim3(TSPLIT, BATCH), 256, 0, stream>>>(xf, sprefix, ghist);
  tpick<2><<<BATCH, 256, 0, stream>>>(ghist, sprefix, sk, tau, rrem);
  thist<3><<<dim3(TSPLIT, BATCH), 256, 0, stream>>>(xf, sprefix, ghist);
  tpick<3><<<BATCH, 256, 0, stream>>>(ghist, sprefix, sk, tau, rrem);

  build_k<<<EW_BLK, 256, 0, stream>>>(xf, tau, dl, eqcnt, eqidx);
  eqfix_k<<<BATCH, 256, 0, stream>>>(dl, xf, eqcnt, eqidx, rrem);
  diag_k<<<(BATCH * NNODE + 255) / 256, 256, 0, stream>>>(dl);
  deg_k<<<(BATCH * NNODE + 255) / 256, 256, 0, stream>>>(dl, dinv);

  // ---- post-top-k GCN: MFMA bf16 split-3 ----
  // G5: xwfrag = dinv[i] * (x2 @ gcn1_w)   (frag-out)
  mfgemm<false, true, false, false><<<dim3(7, BATCH), 256, 0, stream>>>(
      xf, NN, NNODE, w1frag, 0, KC400, nullptr, dinv,
      nullptr, 0, xwfrag, sXW, KC400, NNODE, NNODE);
  // G6: h = relu(dinv[j] * (A^T @ xws) + gcn1_b)
  mfgemm<true, false, true, true><<<dim3(7, BATCH), 256, 0, stream>>>(
      dl, NN, NNODE, xwfrag, sXW, KC400, gcn1_b, dinv,
      hbuf, (long)NNODE * HID, nullptr, 0, 0, NNODE, NNODE);
  // G7: xwfrag = dinv[i] * (h @ gcn2_w)    (frag-out, K=128)
  mfgemm<false, true, false, false><<<dim3(7, BATCH), 256, 0, stream>>>(
      hbuf, (long)NNODE * HID, HID, w2frag, 0, 4, nullptr, dinv,
      nullptr, 0, xwfrag, sXW, KC400, NNODE, HID);
  // G8: h2 = dinv[j] * (A^T @ ts) + gcn2_b
  mfgemm<true, false, true, false><<<dim3(7, BATCH), 256, 0, stream>>>(
      dl, NN, NNODE, xwfrag, sXW, KC400, gcn2_b, dinv,
      hbuf, (long)NNODE * HID, nullptr, 0, 0, NNODE, NNODE);

  head_k<<<BATCH, HID, 0, stream>>>(hbuf, fc_w, fc_b, out);
}

// Round 8
// 701.879 us; speedup vs baseline: 3.4251x; 1.1501x over previous
//
#include <hip/hip_runtime.h>
#include <hip/hip_bf16.h>
#include <math.h>

#define BATCH 128
#define NNODE 400
#define HID   128
#define NN    (NNODE*NNODE)      // 160000
#define KSEL  32000              // int(NN*0.2)
#define EQCAP 1024
#define EPSF  1e-9f
#define TSPLIT 8
#define SEG   (NN / TSPLIT)      // 20000
#define NT    7                  // ceil(400/64)
#define KC400 14                 // 448/32
#define FRAGS (KC400*4096)       // shorts per plane, K=400pad, N=128
#define PLA   57344              // shorts per plane: 4 kchunks * 28 tiles * 512 (K=128,N=400pad / A: M=400pad,K=128)

// map float -> unsigned so that descending float order == descending unsigned order
__device__ __forceinline__ unsigned tokey(float f) {
  unsigned u = __float_as_uint(f);
  return (u & 0x80000000u) ? ~u : (u | 0x80000000u);
}

// fp32 -> bf16 (RNE) and back, as raw shorts
__device__ __forceinline__ short f2bf(float f) {
  unsigned u = __float_as_uint(f);
  u += 0x7fffu + ((u >> 16) & 1u);
  return (short)(u >> 16);
}
__device__ __forceinline__ float bf2f(short s) {
  return __uint_as_float(((unsigned)(unsigned short)s) << 16);
}

typedef __attribute__((ext_vector_type(8))) short s8v;
typedef __attribute__((ext_vector_type(4))) short s4v;
typedef __attribute__((ext_vector_type(4))) float f4v;

// ---------------------------------------------------------------------------
// 64x64-tile fp32 GEMM (VALU) — only G3 (residual, in-place) still uses this.
// ---------------------------------------------------------------------------
#define BK 16
#define LP 68

template<bool AT, bool BIAS, bool RES, bool RELU, bool TS>
__global__ void __launch_bounds__(256) gemm64(
    const float* __restrict__ A, long sA, int lda,
    const float* __restrict__ B, long sB, int ldb,
    const float* __restrict__ bias,
    const float* __restrict__ Res, long sRes,
    float* __restrict__ C, long sC, int ldc,
    int M, int Nc, int K)
{
  __shared__ float As[BK][LP];
  __shared__ float Bs[BK][LP];
  const int bz = blockIdx.z;
  A += (size_t)bz * sA;
  B += (size_t)bz * sB;
  C += (size_t)bz * sC;
  const float* Rp = RES ? (Res + (size_t)bz * sRes) : nullptr;

  const int n0 = blockIdx.x * 64;
  const int m0 = blockIdx.y * 64;
  const int tid = threadIdx.x;
  const int tx = tid & 15, ty = tid >> 4;
  const bool edgeM = (m0 + 64 > M);
  const bool edgeN = (n0 + 64 > Nc);

  float acc[4][4];
#pragma unroll
  for (int i = 0; i < 4; ++i)
#pragma unroll
    for (int j = 0; j < 4; ++j) acc[i][j] = 0.f;

  for (int k0 = 0; k0 < K; k0 += BK) {
    if (!AT) {
      const int m = tid & 63, g = tid >> 6;
      if (!edgeM) {
        const float4 v = *(const float4*)(A + (size_t)(m0 + m) * lda + k0 + 4 * g);
        As[4 * g + 0][m] = v.x; As[4 * g + 1][m] = v.y;
        As[4 * g + 2][m] = v.z; As[4 * g + 3][m] = v.w;
      } else {
        const int gm = m0 + m;
        const bool ok = gm < M;
#pragma unroll
        for (int j = 0; j < 4; ++j)
          As[4 * g + j][m] = ok ? A[(size_t)gm * lda + k0 + 4 * g + j] : 0.f;
      }
    } else {
      const int k = tid >> 4, mg = tid & 15;
      if (!edgeM) {
        const float4 v = *(const float4*)(A + (size_t)(k0 + k) * lda + m0 + 4 * mg);
        *(float4*)&As[k][4 * mg] = v;
      } else {
#pragma unroll
        for (int j = 0; j < 4; ++j) {
          const int gm = m0 + 4 * mg + j;
          As[k][4 * mg + j] = (gm < M) ? A[(size_t)(k0 + k) * lda + gm] : 0.f;
        }
      }
    }
    {
      const int k = tid >> 4, ng = tid & 15;
      if (!edgeN) {
        const float4 v = *(const float4*)(B + (size_t)(k0 + k) * ldb + n0 + 4 * ng);
        *(float4*)&Bs[k][4 * ng] = v;
      } else {
#pragma unroll
        for (int j = 0; j < 4; ++j) {
          const int gn = n0 + 4 * ng + j;
          Bs[k][4 * ng + j] = (gn < Nc) ? B[(size_t)(k0 + k) * ldb + gn] : 0.f;
        }
      }
    }
    __syncthreads();
#pragma unroll
    for (int kk = 0; kk < BK; ++kk) {
      const float4 a = *(const float4*)&As[kk][ty << 2];
      const float4 b = *(const float4*)&Bs[kk][tx << 2];
      const float av[4] = {a.x, a.y, a.z, a.w};
      const float bv[4] = {b.x, b.y, b.z, b.w};
#pragma unroll
      for (int i = 0; i < 4; ++i)
#pragma unroll
        for (int j = 0; j < 4; ++j) acc[i][j] += av[i] * bv[j];
    }
    __syncthreads();
  }

#pragma unroll
  for (int i = 0; i < 4; ++i) {
    const int m = m0 + (ty << 2) + i;
    if (m >= M) continue;
#pragma unroll
    for (int j = 0; j < 4; ++j) {
      const int n = n0 + (tx << 2) + j;
      if (n >= Nc) continue;
      float v = acc[i][j];
      if (BIAS) v += bias[n];
      const size_t loc = TS ? ((size_t)n * ldc + m) : ((size_t)m * ldc + n);
      if (RES) v += Rp[loc];
      if (RELU) v = fmaxf(v, 0.f);
      C[loc] = v;
    }
  }
}

// ---------------------------------------------------------------------------
// bsplitN: W[K][N] fp32 -> MFMA B-fragment bf16 hi/lo planes (Kpad x Npad).
// ---------------------------------------------------------------------------
__global__ void bsplitN(const float* __restrict__ W, int K, int Kpad,
                        int N, int Npad, short* __restrict__ out) {
  int t = blockIdx.x * 256 + threadIdx.x;
  if (t >= Kpad * Npad) return;
  int k = t / Npad, n = t - k * Npad;
  float v = (k < K && n < N) ? W[(size_t)k * N + n] : 0.f;
  short hi = f2bf(v);
  short lo = f2bf(v - bf2f(hi));
  int ntiles = Npad >> 4;
  size_t idx = (((size_t)(k >> 5) * ntiles + (n >> 4)) * 64
                + (((k >> 3) & 3) * 16 + (n & 15))) * 8 + (k & 7);
  size_t PL = (size_t)(Kpad >> 5) * ntiles * 512;
  out[idx] = hi;
  out[PL + idx] = lo;
}

// ---------------------------------------------------------------------------
// afrag: o1 [B][128k][400m] fp32 -> A-fragment bf16 hi/lo planes (per sample).
// A-frag: [c=k>>5][mtile=m>>4][lane=((k>>3)&3)*16+(m&15)][j=k&7], plane PLA.
// ---------------------------------------------------------------------------
__global__ void afrag(const float* __restrict__ src, short* __restrict__ dst) {
  int t = blockIdx.x * 256 + threadIdx.x;
  if (t >= BATCH * 4 * 4 * 28 * 16) return;
  int l = t & 15; t >>= 4;
  int mt = t % 28; t /= 28;
  int quad = t & 3; t >>= 2;
  int c = t & 3; t >>= 2;
  int b = t;
  int m = mt * 16 + l;
  int kb = c * 32 + quad * 8;
  const float* p = src + (size_t)b * HID * NNODE + (size_t)kb * NNODE + m;
  s8v hi, lo;
#pragma unroll
  for (int j = 0; j < 8; ++j) {
    float v = (m < NNODE) ? p[(size_t)j * NNODE] : 0.f;
    short h = f2bf(v);
    hi[j] = h; lo[j] = f2bf(v - bf2f(h));
  }
  size_t o = (size_t)b * 2 * PLA + (((size_t)c * 28 + mt) * 64 + quad * 16 + l) * 8;
  *(s8v*)(dst + o) = hi;
  *(s8v*)(dst + o + PLA) = lo;
}

// ---------------------------------------------------------------------------
// MFMA GEMM (bf16 split-3), N fixed 128.
// C[m,n] = act( [scl[m]*] sum_k A[m,k]*B[k,n] + bias[n] )
// AT: A[m][k]=Araw[k*lda+m].  FRAG: emit frag-ordered bf16 hi/lo (next B).
// TS: store transposed C^T[n][m] (ldc = row stride), via LDS.
// ---------------------------------------------------------------------------
template<bool AT, bool FRAG, bool BIAS, bool RELU, bool SCL, bool TS>
__global__ void __launch_bounds__(256) mfgemm(
    const float* __restrict__ A, long sA, int lda,
    const short* __restrict__ Bf, long sB, int kc,
    const float* __restrict__ bias,
    const float* __restrict__ scl,
    float* __restrict__ Cf, long sCf, int ldc,
    short* __restrict__ Cfrag, long sCfrag, int okc,
    int M, int K)
{
  __shared__ float As[64][68];
  const int bz = blockIdx.y;
  A += (size_t)bz * sA;
  Bf += (size_t)bz * sB;
  if (SCL) scl += (size_t)bz * NNODE;
  if (!FRAG) Cf += (size_t)bz * sCf;
  else       Cfrag += (size_t)bz * sCfrag;

  const int tid = threadIdx.x;
  const int lane = tid & 63, wave = tid >> 6;
  const int wqm = wave >> 1, wqn = wave & 1;
  const int quad = lane >> 4, l15 = lane & 15;
  const int m0 = blockIdx.x * 64;

  f4v acc[2][4];
#pragma unroll
  for (int i = 0; i < 2; ++i)
#pragma unroll
    for (int j = 0; j < 4; ++j) acc[i][j] = (f4v){0.f, 0.f, 0.f, 0.f};

  const int nstage = (K + 63) >> 6;
  for (int st = 0; st < nstage; ++st) {
    const int k0 = st << 6;
    if (st) __syncthreads();
    if (!AT) {
      const int mrow = tid >> 4;
      const int k4 = (tid & 15) << 2;
#pragma unroll
      for (int u = 0; u < 4; ++u) {
        const int m = mrow + (u << 4);
        const int gm = m0 + m, gk = k0 + k4;
        float4 v = {0.f, 0.f, 0.f, 0.f};
        if (gm < M) {
          if (gk + 4 <= K) v = *(const float4*)(A + (size_t)gm * lda + gk);
          else {
            float* pv = (float*)&v;
#pragma unroll
            for (int j = 0; j < 4; ++j)
              if (gk + j < K) pv[j] = A[(size_t)gm * lda + gk + j];
          }
        }
        *(float4*)&As[m][k4] = v;
      }
    } else {
      const int kk = tid >> 4;
      const int m4 = (tid & 15) << 2;
#pragma unroll
      for (int u = 0; u < 4; ++u) {
        const int gk = k0 + kk + (u << 4);
        float4 v = {0.f, 0.f, 0.f, 0.f};
        if (gk < K) {
          if (m0 + m4 + 4 <= M) v = *(const float4*)(A + (size_t)gk * lda + m0 + m4);
          else {
            float* pv = (float*)&v;
#pragma unroll
            for (int j = 0; j < 4; ++j)
              if (m0 + m4 + j < M) pv[j] = A[(size_t)gk * lda + m0 + m4 + j];
          }
        }
        As[m4 + 0][kk + (u << 4)] = v.x;
        As[m4 + 1][kk + (u << 4)] = v.y;
        As[m4 + 2][kk + (u << 4)] = v.z;
        As[m4 + 3][kk + (u << 4)] = v.w;
      }
    }
    __syncthreads();

#pragma unroll
    for (int c2 = 0; c2 < 2; ++c2) {
      const int c = (st << 1) + c2;
      s8v bhi[4], blo[4];
#pragma unroll
      for (int nt = 0; nt < 4; ++nt) {
        const int ntg = (wqn << 2) + nt;
        const size_t off = (((size_t)c * 8 + ntg) * 64 + lane) * 8;
        bhi[nt] = *(const s8v*)(Bf + off);
        blo[nt] = *(const s8v*)(Bf + (size_t)kc * 4096 + off);
      }
#pragma unroll
      for (int mt = 0; mt < 2; ++mt) {
        const int row = (wqm << 5) + (mt << 4) + l15;
        const int kof = (c2 << 5) + (quad << 3);
        const f4v a0 = *(const f4v*)&As[row][kof];
        const f4v a1 = *(const f4v*)&As[row][kof + 4];
        s8v ah, al;
#pragma unroll
        for (int j = 0; j < 4; ++j) {
          short h0 = f2bf(a0[j]); ah[j] = h0; al[j] = f2bf(a0[j] - bf2f(h0));
          short h1 = f2bf(a1[j]); ah[j + 4] = h1; al[j + 4] = f2bf(a1[j] - bf2f(h1));
        }
#pragma unroll
        for (int nt = 0; nt < 4; ++nt) {
          acc[mt][nt] = __builtin_amdgcn_mfma_f32_16x16x32_bf16(ah, bhi[nt], acc[mt][nt], 0, 0, 0);
          acc[mt][nt] = __builtin_amdgcn_mfma_f32_16x16x32_bf16(ah, blo[nt], acc[mt][nt], 0, 0, 0);
          acc[mt][nt] = __builtin_amdgcn_mfma_f32_16x16x32_bf16(al, bhi[nt], acc[mt][nt], 0, 0, 0);
        }
      }
    }
  }

  // ---- epilogue ----
  if (TS) {
    // C^T[n][m] via LDS, two 64-col halves
    for (int nh = 0; nh < 2; ++nh) {
      __syncthreads();
      if (wqn == nh) {
#pragma unroll
        for (int mt = 0; mt < 2; ++mt)
#pragma unroll
          for (int nt = 0; nt < 4; ++nt) {
            const int tn = (nt << 4) + l15;
            const int n  = (wqn << 6) + tn;
            const int mc = (wqm << 5) + (mt << 4) + (quad << 2);
            const f4v a = acc[mt][nt];
#pragma unroll
            for (int reg = 0; reg < 4; ++reg) {
              float v = a[reg];
              if (SCL) v *= scl[m0 + mc + reg];
              if (BIAS) v += bias[n];
              if (RELU) v = fmaxf(v, 0.f);
              As[tn][mc + reg] = v;
            }
          }
      }
      __syncthreads();
      const int row = tid >> 2, cq = tid & 3;
#pragma unroll
      for (int u = 0; u < 4; ++u) {
        const int col = (cq + (u << 2)) << 2;
        if (m0 + col + 4 <= M) {
          const float4 v = *(const float4*)&As[row][col];
          *(float4*)(Cf + (size_t)((nh << 6) + row) * ldc + m0 + col) = v;
        }
      }
    }
    return;
  }

#pragma unroll
  for (int mt = 0; mt < 2; ++mt) {
    const int mb = m0 + (wqm << 5) + (mt << 4) + (quad << 2);
#pragma unroll
    for (int nt = 0; nt < 4; ++nt) {
      const int n = (wqn << 6) + (nt << 4) + l15;
      const f4v a = acc[mt][nt];
      if (!FRAG) {
#pragma unroll
        for (int reg = 0; reg < 4; ++reg) {
          const int m = mb + reg;
          if (m < M) {
            float v = a[reg];
            if (SCL) v *= scl[m];
            if (BIAS) v += bias[n];
            if (RELU) v = fmaxf(v, 0.f);
            Cf[(size_t)m * ldc + n] = v;
          }
        }
      } else {
        s4v h4, l4;
#pragma unroll
        for (int reg = 0; reg < 4; ++reg) {
          const int m = mb + reg;
          float v = (m < M) ? (SCL ? a[reg] * scl[m] : a[reg]) : 0.f;
          short hh = f2bf(v);
          h4[reg] = hh; l4[reg] = f2bf(v - bf2f(hh));
        }
        const int chunkT = mb >> 5, quadT = (mb >> 3) & 3, jT0 = mb & 7;
        const size_t off = (((size_t)chunkT * 8 + (wqn << 2) + nt) * 64
                            + quadT * 16 + l15) * 8 + jT0;
        *(s4v*)(Cfrag + off) = h4;
        *(s4v*)(Cfrag + (size_t)okc * 4096 + off) = l4;
      }
    }
  }
}

// ---------------------------------------------------------------------------
// g4mf: MFMA split-3 pair-tile delta + symmetrize + x2 + pass-0 histogram.
// A frags from o1f (global, pre-split); B frags from dfrag (dec1_w).
// Waves 0/1: delta(I,J) rows; waves 2/3: delta(J,I) rows -> LDS exchange.
// ---------------------------------------------------------------------------
__global__ void __launch_bounds__(256) g4mf(
    const short* __restrict__ o1f,   // [B][2*PLA]
    const short* __restrict__ wfrag, // dec1_w frags, 2 planes of PLA
    const float* __restrict__ bias,  // dec1_b
    float* __restrict__ xf,          // in-place -> x2
    unsigned* __restrict__ ghist)
{
  __shared__ float D2[64][68];
  __shared__ unsigned hist[8][256];
  const int b = blockIdx.y;
  int p = blockIdx.x, bi = 0;
  while (p >= NT - bi) { p -= NT - bi; ++bi; }
  const int bj = bi + p;
  const int I0 = bi * 64, J0 = bj * 64;
  const bool diag = (bi == bj);

  o1f += (size_t)b * 2 * PLA;
  xf += (size_t)b * NN;
  unsigned* gh = ghist + b * 256;

  const int tid = threadIdx.x;
  const int lane = tid & 63, wave = tid >> 6;
  const int wq = wave & 1;
  const bool d1 = wave < 2;
  const int At = (d1 ? bi : bj) * 4;   // A mtile base
  const int Bt = (d1 ? bj : bi) * 4;   // B ntile base
  const int quad = lane >> 4, l15 = lane & 15;

  for (int i = tid; i < 8 * 256; i += 256) ((unsigned*)hist)[i] = 0u;

  f4v acc[2][4];
#pragma unroll
  for (int i = 0; i < 2; ++i)
#pragma unroll
    for (int j = 0; j < 4; ++j) acc[i][j] = (f4v){0.f, 0.f, 0.f, 0.f};

  for (int c = 0; c < 4; ++c) {
    s8v ahi[2], alo[2];
#pragma unroll
    for (int mt = 0; mt < 2; ++mt) {
      const int mtg = At + (wq << 1) + mt;
      const size_t off = (((size_t)c * 28 + mtg) * 64 + lane) * 8;
      ahi[mt] = *(const s8v*)(o1f + off);
      alo[mt] = *(const s8v*)(o1f + PLA + off);
    }
    s8v bhi[4], blo[4];
#pragma unroll
    for (int nt = 0; nt < 4; ++nt) {
      const int ntg = Bt + nt;
      const size_t off = (((size_t)c * 28 + ntg) * 64 + lane) * 8;
      bhi[nt] = *(const s8v*)(wfrag + off);
      blo[nt] = *(const s8v*)(wfrag + PLA + off);
    }
#pragma unroll
    for (int mt = 0; mt < 2; ++mt)
#pragma unroll
      for (int nt = 0; nt < 4; ++nt) {
        acc[mt][nt] = __builtin_amdgcn_mfma_f32_16x16x32_bf16(ahi[mt], bhi[nt], acc[mt][nt], 0, 0, 0);
        acc[mt][nt] = __builtin_amdgcn_mfma_f32_16x16x32_bf16(ahi[mt], blo[nt], acc[mt][nt], 0, 0, 0);
        acc[mt][nt] = __builtin_amdgcn_mfma_f32_16x16x32_bf16(alo[mt], bhi[nt], acc[mt][nt], 0, 0, 0);
      }
  }
  __syncthreads();

  // waves 2/3: dump delta2[m'][n'] (m' = J-row local, n' = I-col local) to LDS
  if (!d1) {
#pragma unroll
    for (int mt = 0; mt < 2; ++mt) {
      const int mb = (wq << 5) + (mt << 4) + (quad << 2);
#pragma unroll
      for (int nt = 0; nt < 4; ++nt) {
        const int nn = (nt << 4) + l15;
        const f4v a = acc[mt][nt];
#pragma unroll
        for (int reg = 0; reg < 4; ++reg) D2[mb + reg][nn] = a[reg];
      }
    }
  }
  __syncthreads();

  // waves 0/1: form x2 tile (I,J), write both (I,J) and (J,I), histogram
  if (d1) {
    const int rep = tid & 7;
#pragma unroll
    for (int mt = 0; mt < 2; ++mt) {
      const int a0 = (wq << 5) + (mt << 4) + (quad << 2);
#pragma unroll
      for (int nt = 0; nt < 4; ++nt) {
        const int nn = (nt << 4) + l15;
        const int gj = J0 + nn;
        const f4v d1v = acc[mt][nt];
        const f4v d2t = *(const f4v*)&D2[nn][a0];   // delta[J0+nn][I0+a0+reg]
        f4v vv;
#pragma unroll
        for (int reg = 0; reg < 4; ++reg) {
          const int gi = I0 + a0 + reg;
          float v = 0.f;
          if (gi < NNODE && gj < NNODE) {
            v = xf[(size_t)gi * NNODE + gj];
            if (gi != gj)
              v += 0.5f * (d1v[reg] + d2t[reg] + bias[gj] + bias[gi]);
            atomicAdd(&hist[rep][tokey(v) >> 24], diag ? 1u : 2u);
          }
          vv[reg] = v;
        }
        // (I,J) write: coalesced scalars
#pragma unroll
        for (int reg = 0; reg < 4; ++reg) {
          const int gi = I0 + a0 + reg;
          if (gi < NNODE && gj < NNODE) xf[(size_t)gi * NNODE + gj] = vv[reg];
        }
        // (J,I) transpose write (x2 symmetric): float4 rows
        if (!diag && gj < NNODE && (I0 + a0 + 4 <= NNODE)) {
          *(float4*)(xf + (size_t)gj * NNODE + I0 + a0) = *(float4*)&vv;
        }
      }
    }
  }
  __syncthreads();
  if (tid < 256) {
    const unsigned s = hist[0][tid] + hist[1][tid] + hist[2][tid] + hist[3][tid]
                     + hist[4][tid] + hist[5][tid] + hist[6][tid] + hist[7][tid];
    if (s) atomicAdd(&gh[tid], s);
  }
}

// ---------------------------------------------------------------------------
__global__ void denom_k(const float* __restrict__ x, float* __restrict__ denom) {
  int b = threadIdx.x;
  if (b < BATCH) {
    float v = x[(size_t)b * NN];
    denom[b] = 0.5f * logf((1.0f + v + EPSF) / (1.0f - v + EPSF));
  }
}

__global__ void xf_k(const float* __restrict__ x, const float* __restrict__ denom,
                     float* __restrict__ xf) {
  size_t e = (size_t)blockIdx.x * 256 + threadIdx.x;
  if (e >= (size_t)BATCH * NN) return;
  int b = (int)(e / NN);
  float v = x[e];
  float t = 0.5f * logf((1.0f + v + EPSF) / (1.0f - v + EPSF));
  xf[e] = t / denom[b];
}

// ---------------------------------------------------------------------------
__global__ void tz_init(unsigned* __restrict__ ghist, unsigned* __restrict__ sprefix,
                        int* __restrict__ sk, int* __restrict__ eqcnt) {
  int t = blockIdx.x * 256 + threadIdx.x;
  if (t < BATCH * 256) ghist[t] = 0u;
  if (t < BATCH) { sprefix[t] = 0u; sk[t] = KSEL; eqcnt[t] = 0; }
}

template<int PASS>
__global__ void __launch_bounds__(256) thist(const float* __restrict__ x2,
                                             const unsigned* __restrict__ sprefix,
                                             unsigned* __restrict__ ghist) {
  constexpr int shift = 24 - 8 * PASS;
  __shared__ unsigned h[8][256];
  const int b  = blockIdx.y;
  const int sb = blockIdx.x;
  const int tid = threadIdx.x;
  for (int i = tid; i < 8 * 256; i += 256) ((unsigned*)h)[i] = 0u;
  __syncthreads();

  const unsigned prefix = sprefix[b];
  const unsigned pmask  = 0xFFFFFFFFu << (shift + 8);
  const int rep = tid & 7;
  const float4* p4 = (const float4*)(x2 + (size_t)b * NN);
  const int i0 = sb * (SEG / 4), i1 = i0 + (SEG / 4);
  for (int i = i0 + tid; i < i1; i += 256) {
    float4 v = p4[i];
    unsigned k0 = tokey(v.x), k1 = tokey(v.y), k2 = tokey(v.z), k3 = tokey(v.w);
    if ((k0 & pmask) == prefix) atomicAdd(&h[rep][(k0 >> shift) & 255u], 1u);
    if ((k1 & pmask) == prefix) atomicAdd(&h[rep][(k1 >> shift) & 255u], 1u);
    if ((k2 & pmask) == prefix) atomicAdd(&h[rep][(k2 >> shift) & 255u], 1u);
    if ((k3 & pmask) == prefix) atomicAdd(&h[rep][(k3 >> shift) & 255u], 1u);
  }
  __syncthreads();
  if (tid < 256) {
    unsigned s = h[0][tid] + h[1][tid] + h[2][tid] + h[3][tid]
               + h[4][tid] + h[5][tid] + h[6][tid] + h[7][tid];
    if (s) atomicAdd(&ghist[b * 256 + tid], s);
  }
}

template<int PASS>
__global__ void __launch_bounds__(256) tpick(unsigned* __restrict__ ghist,
                                             unsigned* __restrict__ sprefix,
                                             int* __restrict__ sk,
                                             unsigned* __restrict__ tau,
                                             int* __restrict__ rrem) {
  constexpr int shift = 24 - 8 * PASS;
  const int b = blockIdx.x;
  __shared__ unsigned h[256];
  h[threadIdx.x] = ghist[b * 256 + threadIdx.x];
  __syncthreads();
  if (threadIdx.x == 0) {
    int k = sk[b];
    unsigned byte = 0u;
    for (int bin = 255; bin >= 0; --bin) {
      int c = (int)h[bin];
      if (c >= k) { byte = (unsigned)bin; break; }
      k -= c;
    }
    unsigned np = sprefix[b] | (byte << shift);
    sprefix[b] = np; sk[b] = k;
    if (PASS == 3) { tau[b] = np; rrem[b] = k; }
  }
  ghist[b * 256 + threadIdx.x] = 0u;
}

__global__ void build_k(const float* __restrict__ x2, const unsigned* __restrict__ tau,
                        float* __restrict__ A, int* __restrict__ eqcnt,
                        int* __restrict__ eqidx) {
  size_t e = (size_t)blockIdx.x * 256 + threadIdx.x;
  if (e >= (size_t)BATCH * NN) return;
  int b = (int)(e / NN);
  int i = (int)(e - (size_t)b * NN);
  float v = x2[e];
  unsigned key = tokey(v);
  unsigned tk = tau[b];
  A[e] = (key > tk) ? v : 0.f;
  if (key == tk) {
    int p = atomicAdd(&eqcnt[b], 1);
    if (p < EQCAP) eqidx[b * EQCAP + p] = i;
  }
}

__global__ void eqfix_k(float* __restrict__ A, const float* __restrict__ x2,
                        const int* __restrict__ eqcnt, const int* __restrict__ eqidx,
                        const int* __restrict__ rrem) {
  int b = blockIdx.x;
  int cnt = eqcnt[b]; if (cnt > EQCAP) cnt = EQCAP;
  int r = rrem[b];
  for (int t = threadIdx.x; t < cnt; t += 256) {
    int idx = eqidx[b * EQCAP + t];
    int rank = 0;
    for (int u = 0; u < cnt; ++u) rank += (eqidx[b * EQCAP + u] < idx) ? 1 : 0;
    if (rank < r) A[(size_t)b * NN + idx] = x2[(size_t)b * NN + idx];
  }
}

__global__ void diag_k(float* __restrict__ A) {
  int t = blockIdx.x * blockDim.x + threadIdx.x;
  if (t >= BATCH * NNODE) return;
  int b = t / NNODE, i = t - b * NNODE;
  size_t o = (size_t)b * NN + (size_t)i * NNODE + i;
  if (A[o] == 0.f) A[o] = 1.0f;
}

__global__ void deg_k(const float* __restrict__ A, float* __restrict__ dinv) {
  int t = blockIdx.x * blockDim.x + threadIdx.x;
  if (t >= BATCH * NNODE) return;
  int b = t / NNODE, j = t - b * NNODE;
  const float* p = A + (size_t)b * NN + j;
  float s = 0.f;
  for (int i = 0; i < NNODE; ++i) s += p[(size_t)i * NNODE];
  dinv[t] = (s == 0.f) ? 0.f : 1.0f / sqrtf(s);
}

__global__ void head_k(const float* __restrict__ h2, const float* __restrict__ fc_w,
                       const float* __restrict__ fc_b, float* __restrict__ out) {
  int b = blockIdx.x;
  int f = threadIdx.x;
  float s = 0.f;
  const float* p = h2 + (size_t)b * NNODE * HID + f;
  for (int j = 0; j < NNODE; ++j) s += p[(size_t)j * HID];
  float pv = fmaxf(s / (float)NNODE, 0.f);
  __shared__ float r0[128], r1[128];
  r0[f] = pv * fc_w[f * 2 + 0];
  r1[f] = pv * fc_w[f * 2 + 1];
  __syncthreads();
  for (int sft = 64; sft > 0; sft >>= 1) {
    if (f < sft) { r0[f] += r0[f + sft]; r1[f] += r1[f + sft]; }
    __syncthreads();
  }
  if (f == 0) {
    out[b * 2 + 0] = r0[0] + fc_b[0];
    out[b * 2 + 1] = r1[0] + fc_b[1];
  }
}

// ---------------------------------------------------------------------------
extern "C" void kernel_launch(void* const* d_in, const int* in_sizes, int n_in,
                              void* d_out, int out_size, void* d_ws, size_t ws_size,
                              hipStream_t stream) {
  const float* x      = (const float*)d_in[0];
  const float* enc1_w = (const float*)d_in[2];
  const float* enc1_b = (const float*)d_in[3];
  const float* enc2_w = (const float*)d_in[4];
  const float* enc2_b = (const float*)d_in[5];
  const float* dec2_w = (const float*)d_in[6];
  const float* dec2_b = (const float*)d_in[7];
  const float* dec1_w = (const float*)d_in[8];
  const float* dec1_b = (const float*)d_in[9];
  const float* gcn1_w = (const float*)d_in[10];
  const float* gcn1_b = (const float*)d_in[11];
  const float* gcn2_w = (const float*)d_in[12];
  const float* gcn2_b = (const float*)d_in[13];
  const float* fc_w   = (const float*)d_in[14];
  const float* fc_b   = (const float*)d_in[15];
  float* out = (float*)d_out;
  (void)in_sizes; (void)n_in; (void)out_size; (void)ws_size;

  float* ws = (float*)d_ws;
  size_t off = 0;
  auto take = [&](size_t n) { float* p = ws + off; off += (n + 63) & ~(size_t)63; return p; };
  float* xf   = take((size_t)BATCH * NN);          // xf -> x2 (in place)
  float* dl   = take((size_t)BATCH * NN);          // o1f alias, then A (sparsified)
  float* o1   = take((size_t)BATCH * HID * NNODE); // out1 -> out2b; later xwfrag alias
  float* o2   = take((size_t)BATCH * HID * HID);
  float* hbuf = take((size_t)BATCH * NNODE * HID); // h -> h2
  float* denom = take(BATCH);
  float* dinv  = take((size_t)BATCH * NNODE);
  unsigned* tau = (unsigned*)take(BATCH);
  int* rrem  = (int*)take(BATCH);
  int* eqcnt = (int*)take(BATCH);
  int* eqidx = (int*)take((size_t)BATCH * EQCAP);
  unsigned* ghist   = (unsigned*)take((size_t)BATCH * 256);
  unsigned* sprefix = (unsigned*)take(BATCH);
  int*      sk      = (int*)take(BATCH);
  short* w1frag = (short*)take((size_t)FRAGS + 64);          // gcn1_w, 2 planes K448
  short* w2frag = (short*)take((size_t)4 * 4096 + 64);       // gcn2_w, 2 planes K128
  short* e1frag = (short*)take((size_t)FRAGS + 64);          // enc1_w
  short* e2frag = (short*)take((size_t)FRAGS + 64);          // enc2_w
  short* dfrag  = (short*)take((size_t)PLA + 64);            // dec1_w (2*PLA shorts)
  short* xwfrag = (short*)o1;          // aliases dead o1 (post-afrag)
  short* o1f    = (short*)dl;          // aliases dl (dead until build_k)
  const long sXW = 2L * FRAGS;

  const size_t TOT = (size_t)BATCH * NN;
  const int EW_BLK = (int)((TOT + 255) / 256);

  tz_init<<<128, 256, 0, stream>>>(ghist, sprefix, sk, eqcnt);
  denom_k<<<1, BATCH, 0, stream>>>(x, denom);
  xf_k<<<EW_BLK, 256, 0, stream>>>(x, denom, xf);
  bsplitN<<<224, 256, 0, stream>>>(gcn1_w, NNODE, 448, HID, 128, w1frag);
  bsplitN<<<64,  256, 0, stream>>>(gcn2_w, HID, 128, HID, 128, w2frag);
  bsplitN<<<224, 256, 0, stream>>>(enc1_w, NNODE, 448, HID, 128, e1frag);
  bsplitN<<<224, 256, 0, stream>>>(enc2_w, NNODE, 448, HID, 128, e2frag);
  bsplitN<<<224, 256, 0, stream>>>(dec1_w, HID, 128, NNODE, 448, dfrag);

  // G1: o1 = (relu(xf @ enc1_w + b))^T  — MFMA split-3, transposed store
  mfgemm<false, false, true, true, false, true><<<dim3(7, BATCH), 256, 0, stream>>>(
      xf, NN, NNODE, e1frag, 0, KC400, enc1_b, nullptr,
      o1, (long)HID * NNODE, NNODE, nullptr, 0, 0, NNODE, NNODE);
  // G2: o2 = relu(o1 @ enc2_w + b)      — MFMA split-3
  mfgemm<false, false, true, true, false, false><<<dim3(2, BATCH), 256, 0, stream>>>(
      o1, (long)HID * NNODE, NNODE, e2frag, 0, KC400, enc2_b, nullptr,
      o2, (long)HID * HID, HID, nullptr, 0, 0, HID, NNODE);
  // G3: out2b = relu(o2 @ dec2_w + b + o1), in-place (fp32)
  gemm64<false, true, true, true, false><<<dim3(7, 2, BATCH), 256, 0, stream>>>(
      o2, (long)HID * HID, HID, dec2_w, 0, NNODE, dec2_b,
      o1, (long)HID * NNODE, o1, (long)HID * NNODE, NNODE, HID, NNODE, HID);

  // split o1 into A-fragment planes, then fused delta+x2+hist (MFMA split-3)
  afrag<<<3584, 256, 0, stream>>>(o1, o1f);
  g4mf<<<dim3(NT * (NT + 1) / 2, BATCH), 256, 0, stream>>>(o1f, dfrag, dec1_b, xf, ghist);

  tpick<0><<<BATCH, 256, 0, stream>>>(ghist, sprefix, sk, tau, rrem);
  thist<1><<<dim3(TSPLIT, BATCH), 256, 0, stream>>>(xf, sprefix, ghist);
  tpick<1><<<BATCH, 256, 0, stream>>>(ghist, sprefix, sk, tau, rrem);
  thist<2><<<dim3(TSPLIT, BATCH), 256, 0, stream>>>(xf, sprefix, ghist);
  tpick<2><<<BATCH, 256, 0, stream>>>(ghist, sprefix, sk, tau, rrem);
  thist<3><<<dim3(TSPLIT, BATCH), 256, 0, stream>>>(xf, sprefix, ghist);
  tpick<3><<<BATCH, 256, 0, stream>>>(ghist, sprefix, sk, tau, rrem);

  build_k<<<EW_BLK, 256, 0, stream>>>(xf, tau, dl, eqcnt, eqidx);
  eqfix_k<<<BATCH, 256, 0, stream>>>(dl, xf, eqcnt, eqidx, rrem);
  diag_k<<<(BATCH * NNODE + 255) / 256, 256, 0, stream>>>(dl);
  deg_k<<<(BATCH * NNODE + 255) / 256, 256, 0, stream>>>(dl, dinv);

  // ---- post-top-k GCN: MFMA bf16 split-3 (unchanged from R7) ----
  mfgemm<false, true, false, false, true, false><<<dim3(7, BATCH), 256, 0, stream>>>(
      xf, NN, NNODE, w1frag, 0, KC400, nullptr, dinv,
      nullptr, 0, 128, xwfrag, sXW, KC400, NNODE, NNODE);
  mfgemm<true, false, true, true, true, false><<<dim3(7, BATCH), 256, 0, stream>>>(
      dl, NN, NNODE, xwfrag, sXW, KC400, gcn1_b, dinv,
      hbuf, (long)NNODE * HID, HID, nullptr, 0, 0, NNODE, NNODE);
  mfgemm<false, true, false, false, true, false><<<dim3(7, BATCH), 256, 0, stream>>>(
      hbuf, (long)NNODE * HID, HID, w2frag, 0, 4, nullptr, dinv,
      nullptr, 0, 128, xwfrag, sXW, KC400, NNODE, HID);
  mfgemm<true, false, true, false, true, false><<<dim3(7, BATCH), 256, 0, stream>>>(
      dl, NN, NNODE, xwfrag, sXW, KC400, gcn2_b, dinv,
      hbuf, (long)NNODE * HID, HID, nullptr, 0, 0, NNODE, NNODE);

  head_k<<<BATCH, HID, 0, stream>>>(hbuf, fc_w, fc_b, out);
}

// Round 9
// 690.624 us; speedup vs baseline: 3.4809x; 1.0163x over previous
//
#include <hip/hip_runtime.h>
#include <hip/hip_bf16.h>
#include <math.h>

#define BATCH 128
#define NNODE 400
#define HID   128
#define NN    (NNODE*NNODE)      // 160000
#define KSEL  32000              // int(NN*0.2)
#define EQCAP 1024
#define EPSF  1e-9f
#define TSPLIT 8
#define SEG   (NN / TSPLIT)      // 20000
#define NT    7                  // ceil(400/64)
#define KC400 14                 // 448/32
#define FRAGS (KC400*4096)       // shorts per plane, K=400pad, N=128
#define PLA   57344              // shorts per plane: 4 kchunks * 28 ntiles * 512 (dec1_w: K=128, N=448pad)

// map float -> unsigned so that descending float order == descending unsigned order
__device__ __forceinline__ unsigned tokey(float f) {
  unsigned u = __float_as_uint(f);
  return (u & 0x80000000u) ? ~u : (u | 0x80000000u);
}

// fp32 -> bf16 (RNE) and back, as raw shorts
__device__ __forceinline__ short f2bf(float f) {
  unsigned u = __float_as_uint(f);
  u += 0x7fffu + ((u >> 16) & 1u);
  return (short)(u >> 16);
}
__device__ __forceinline__ float bf2f(short s) {
  return __uint_as_float(((unsigned)(unsigned short)s) << 16);
}

typedef __attribute__((ext_vector_type(8))) short s8v;
typedef __attribute__((ext_vector_type(4))) short s4v;
typedef __attribute__((ext_vector_type(4))) float f4v;

// ---------------------------------------------------------------------------
// 64x64-tile fp32 GEMM (VALU) — only G3 (residual, in-place) still uses this.
// ---------------------------------------------------------------------------
#define BK 16
#define LP 68

template<bool AT, bool BIAS, bool RES, bool RELU, bool TS>
__global__ void __launch_bounds__(256) gemm64(
    const float* __restrict__ A, long sA, int lda,
    const float* __restrict__ B, long sB, int ldb,
    const float* __restrict__ bias,
    const float* __restrict__ Res, long sRes,
    float* __restrict__ C, long sC, int ldc,
    int M, int Nc, int K)
{
  __shared__ float As[BK][LP];
  __shared__ float Bs[BK][LP];
  const int bz = blockIdx.z;
  A += (size_t)bz * sA;
  B += (size_t)bz * sB;
  C += (size_t)bz * sC;
  const float* Rp = RES ? (Res + (size_t)bz * sRes) : nullptr;

  const int n0 = blockIdx.x * 64;
  const int m0 = blockIdx.y * 64;
  const int tid = threadIdx.x;
  const int tx = tid & 15, ty = tid >> 4;
  const bool edgeM = (m0 + 64 > M);
  const bool edgeN = (n0 + 64 > Nc);

  float acc[4][4];
#pragma unroll
  for (int i = 0; i < 4; ++i)
#pragma unroll
    for (int j = 0; j < 4; ++j) acc[i][j] = 0.f;

  for (int k0 = 0; k0 < K; k0 += BK) {
    if (!AT) {
      const int m = tid & 63, g = tid >> 6;
      if (!edgeM) {
        const float4 v = *(const float4*)(A + (size_t)(m0 + m) * lda + k0 + 4 * g);
        As[4 * g + 0][m] = v.x; As[4 * g + 1][m] = v.y;
        As[4 * g + 2][m] = v.z; As[4 * g + 3][m] = v.w;
      } else {
        const int gm = m0 + m;
        const bool ok = gm < M;
#pragma unroll
        for (int j = 0; j < 4; ++j)
          As[4 * g + j][m] = ok ? A[(size_t)gm * lda + k0 + 4 * g + j] : 0.f;
      }
    } else {
      const int k = tid >> 4, mg = tid & 15;
      if (!edgeM) {
        const float4 v = *(const float4*)(A + (size_t)(k0 + k) * lda + m0 + 4 * mg);
        *(float4*)&As[k][4 * mg] = v;
      } else {
#pragma unroll
        for (int j = 0; j < 4; ++j) {
          const int gm = m0 + 4 * mg + j;
          As[k][4 * mg + j] = (gm < M) ? A[(size_t)(k0 + k) * lda + gm] : 0.f;
        }
      }
    }
    {
      const int k = tid >> 4, ng = tid & 15;
      if (!edgeN) {
        const float4 v = *(const float4*)(B + (size_t)(k0 + k) * ldb + n0 + 4 * ng);
        *(float4*)&Bs[k][4 * ng] = v;
      } else {
#pragma unroll
        for (int j = 0; j < 4; ++j) {
          const int gn = n0 + 4 * ng + j;
          Bs[k][4 * ng + j] = (gn < Nc) ? B[(size_t)(k0 + k) * ldb + gn] : 0.f;
        }
      }
    }
    __syncthreads();
#pragma unroll
    for (int kk = 0; kk < BK; ++kk) {
      const float4 a = *(const float4*)&As[kk][ty << 2];
      const float4 b = *(const float4*)&Bs[kk][tx << 2];
      const float av[4] = {a.x, a.y, a.z, a.w};
      const float bv[4] = {b.x, b.y, b.z, b.w};
#pragma unroll
      for (int i = 0; i < 4; ++i)
#pragma unroll
        for (int j = 0; j < 4; ++j) acc[i][j] += av[i] * bv[j];
    }
    __syncthreads();
  }

#pragma unroll
  for (int i = 0; i < 4; ++i) {
    const int m = m0 + (ty << 2) + i;
    if (m >= M) continue;
#pragma unroll
    for (int j = 0; j < 4; ++j) {
      const int n = n0 + (tx << 2) + j;
      if (n >= Nc) continue;
      float v = acc[i][j];
      if (BIAS) v += bias[n];
      const size_t loc = TS ? ((size_t)n * ldc + m) : ((size_t)m * ldc + n);
      if (RES) v += Rp[loc];
      if (RELU) v = fmaxf(v, 0.f);
      C[loc] = v;
    }
  }
}

// ---------------------------------------------------------------------------
// bsplitN: W[K][N] fp32 -> MFMA B-fragment bf16 hi/lo planes (Kpad x Npad).
// ---------------------------------------------------------------------------
__global__ void bsplitN(const float* __restrict__ W, int K, int Kpad,
                        int N, int Npad, short* __restrict__ out) {
  int t = blockIdx.x * 256 + threadIdx.x;
  if (t >= Kpad * Npad) return;
  int k = t / Npad, n = t - k * Npad;
  float v = (k < K && n < N) ? W[(size_t)k * N + n] : 0.f;
  short hi = f2bf(v);
  short lo = f2bf(v - bf2f(hi));
  int ntiles = Npad >> 4;
  size_t idx = (((size_t)(k >> 5) * ntiles + (n >> 4)) * 64
                + (((k >> 3) & 3) * 16 + (n & 15))) * 8 + (k & 7);
  size_t PL = (size_t)(Kpad >> 5) * ntiles * 512;
  out[idx] = hi;
  out[PL + idx] = lo;
}

// ---------------------------------------------------------------------------
// MFMA GEMM (bf16 split-3), N fixed 128.
// C[m,n] = act( [scl[m]*] sum_k A[m,k]*B[k,n] + bias[n] )
// AT: A[m][k]=Araw[k*lda+m].  FRAG: emit frag-ordered bf16 hi/lo (next B).
// TS: store transposed C^T[n][m] via LDS.
// XF (only with !AT): A is raw x; apply fisher transform (t/denom) during
// staging and ALSO write the result to xfout (fuses xf_k into G1).
// ---------------------------------------------------------------------------
template<bool AT, bool FRAG, bool BIAS, bool RELU, bool SCL, bool TS, bool XF>
__global__ void __launch_bounds__(256) mfgemm(
    const float* __restrict__ A, long sA, int lda,
    const short* __restrict__ Bf, long sB, int kc,
    const float* __restrict__ bias,
    const float* __restrict__ scl,
    float* __restrict__ Cf, long sCf, int ldc,
    short* __restrict__ Cfrag, long sCfrag, int okc,
    const float* __restrict__ denomp, float* __restrict__ xfout,
    int M, int K)
{
  __shared__ float As[64][68];
  const int bz = blockIdx.y;
  A += (size_t)bz * sA;
  Bf += (size_t)bz * sB;
  if (SCL) scl += (size_t)bz * NNODE;
  if (!FRAG) Cf += (size_t)bz * sCf;
  else       Cfrag += (size_t)bz * sCfrag;
  if (XF) xfout += (size_t)bz * sA;
  const float dnm = XF ? denomp[bz] : 0.f;

  const int tid = threadIdx.x;
  const int lane = tid & 63, wave = tid >> 6;
  const int wqm = wave >> 1, wqn = wave & 1;
  const int quad = lane >> 4, l15 = lane & 15;
  const int m0 = blockIdx.x * 64;

  f4v acc[2][4];
#pragma unroll
  for (int i = 0; i < 2; ++i)
#pragma unroll
    for (int j = 0; j < 4; ++j) acc[i][j] = (f4v){0.f, 0.f, 0.f, 0.f};

  const int nstage = (K + 63) >> 6;
  for (int st = 0; st < nstage; ++st) {
    const int k0 = st << 6;
    if (st) __syncthreads();
    if (!AT) {
      const int mrow = tid >> 4;
      const int k4 = (tid & 15) << 2;
#pragma unroll
      for (int u = 0; u < 4; ++u) {
        const int m = mrow + (u << 4);
        const int gm = m0 + m, gk = k0 + k4;
        float4 v = {0.f, 0.f, 0.f, 0.f};
        if (gm < M) {
          if (gk + 4 <= K) {
            float4 xv = *(const float4*)(A + (size_t)gm * lda + gk);
            if (XF) {
              v.x = 0.5f * logf((1.0f + xv.x + EPSF) / (1.0f - xv.x + EPSF)) / dnm;
              v.y = 0.5f * logf((1.0f + xv.y + EPSF) / (1.0f - xv.y + EPSF)) / dnm;
              v.z = 0.5f * logf((1.0f + xv.z + EPSF) / (1.0f - xv.z + EPSF)) / dnm;
              v.w = 0.5f * logf((1.0f + xv.w + EPSF) / (1.0f - xv.w + EPSF)) / dnm;
              *(float4*)(xfout + (size_t)gm * lda + gk) = v;
            } else v = xv;
          } else {
            float* pv = (float*)&v;
#pragma unroll
            for (int j = 0; j < 4; ++j)
              if (gk + j < K) {
                float xv = A[(size_t)gm * lda + gk + j];
                if (XF) {
                  pv[j] = 0.5f * logf((1.0f + xv + EPSF) / (1.0f - xv + EPSF)) / dnm;
                  xfout[(size_t)gm * lda + gk + j] = pv[j];
                } else pv[j] = xv;
              }
          }
        }
        *(float4*)&As[m][k4] = v;
      }
    } else {
      const int kk = tid >> 4;
      const int m4 = (tid & 15) << 2;
#pragma unroll
      for (int u = 0; u < 4; ++u) {
        const int gk = k0 + kk + (u << 4);
        float4 v = {0.f, 0.f, 0.f, 0.f};
        if (gk < K) {
          if (m0 + m4 + 4 <= M) v = *(const float4*)(A + (size_t)gk * lda + m0 + m4);
          else {
            float* pv = (float*)&v;
#pragma unroll
            for (int j = 0; j < 4; ++j)
              if (m0 + m4 + j < M) pv[j] = A[(size_t)gk * lda + m0 + m4 + j];
          }
        }
        As[m4 + 0][kk + (u << 4)] = v.x;
        As[m4 + 1][kk + (u << 4)] = v.y;
        As[m4 + 2][kk + (u << 4)] = v.z;
        As[m4 + 3][kk + (u << 4)] = v.w;
      }
    }
    __syncthreads();

#pragma unroll
    for (int c2 = 0; c2 < 2; ++c2) {
      const int c = (st << 1) + c2;
      s8v bhi[4], blo[4];
#pragma unroll
      for (int nt = 0; nt < 4; ++nt) {
        const int ntg = (wqn << 2) + nt;
        const size_t off = (((size_t)c * 8 + ntg) * 64 + lane) * 8;
        bhi[nt] = *(const s8v*)(Bf + off);
        blo[nt] = *(const s8v*)(Bf + (size_t)kc * 4096 + off);
      }
#pragma unroll
      for (int mt = 0; mt < 2; ++mt) {
        const int row = (wqm << 5) + (mt << 4) + l15;
        const int kof = (c2 << 5) + (quad << 3);
        const f4v a0 = *(const f4v*)&As[row][kof];
        const f4v a1 = *(const f4v*)&As[row][kof + 4];
        s8v ah, al;
#pragma unroll
        for (int j = 0; j < 4; ++j) {
          short h0 = f2bf(a0[j]); ah[j] = h0; al[j] = f2bf(a0[j] - bf2f(h0));
          short h1 = f2bf(a1[j]); ah[j + 4] = h1; al[j + 4] = f2bf(a1[j] - bf2f(h1));
        }
#pragma unroll
        for (int nt = 0; nt < 4; ++nt) {
          acc[mt][nt] = __builtin_amdgcn_mfma_f32_16x16x32_bf16(ah, bhi[nt], acc[mt][nt], 0, 0, 0);
          acc[mt][nt] = __builtin_amdgcn_mfma_f32_16x16x32_bf16(ah, blo[nt], acc[mt][nt], 0, 0, 0);
          acc[mt][nt] = __builtin_amdgcn_mfma_f32_16x16x32_bf16(al, bhi[nt], acc[mt][nt], 0, 0, 0);
        }
      }
    }
  }

  // ---- epilogue ----
  if (TS) {
    for (int nh = 0; nh < 2; ++nh) {
      __syncthreads();
      if (wqn == nh) {
#pragma unroll
        for (int mt = 0; mt < 2; ++mt)
#pragma unroll
          for (int nt = 0; nt < 4; ++nt) {
            const int tn = (nt << 4) + l15;
            const int n  = (wqn << 6) + tn;
            const int mc = (wqm << 5) + (mt << 4) + (quad << 2);
            const f4v a = acc[mt][nt];
#pragma unroll
            for (int reg = 0; reg < 4; ++reg) {
              float v = a[reg];
              if (SCL) v *= scl[m0 + mc + reg];
              if (BIAS) v += bias[n];
              if (RELU) v = fmaxf(v, 0.f);
              As[tn][mc + reg] = v;
            }
          }
      }
      __syncthreads();
      const int row = tid >> 2, cq = tid & 3;
#pragma unroll
      for (int u = 0; u < 4; ++u) {
        const int col = (cq + (u << 2)) << 2;
        if (m0 + col + 4 <= M) {
          const float4 v = *(const float4*)&As[row][col];
          *(float4*)(Cf + (size_t)((nh << 6) + row) * ldc + m0 + col) = v;
        }
      }
    }
    return;
  }

#pragma unroll
  for (int mt = 0; mt < 2; ++mt) {
    const int mb = m0 + (wqm << 5) + (mt << 4) + (quad << 2);
#pragma unroll
    for (int nt = 0; nt < 4; ++nt) {
      const int n = (wqn << 6) + (nt << 4) + l15;
      const f4v a = acc[mt][nt];
      if (!FRAG) {
#pragma unroll
        for (int reg = 0; reg < 4; ++reg) {
          const int m = mb + reg;
          if (m < M) {
            float v = a[reg];
            if (SCL) v *= scl[m];
            if (BIAS) v += bias[n];
            if (RELU) v = fmaxf(v, 0.f);
            Cf[(size_t)m * ldc + n] = v;
          }
        }
      } else {
        s4v h4, l4;
#pragma unroll
        for (int reg = 0; reg < 4; ++reg) {
          const int m = mb + reg;
          float v = (m < M) ? (SCL ? a[reg] * scl[m] : a[reg]) : 0.f;
          short hh = f2bf(v);
          h4[reg] = hh; l4[reg] = f2bf(v - bf2f(hh));
        }
        const int chunkT = mb >> 5, quadT = (mb >> 3) & 3, jT0 = mb & 7;
        const size_t off = (((size_t)chunkT * 8 + (wqn << 2) + nt) * 64
                            + quadT * 16 + l15) * 8 + jT0;
        *(s4v*)(Cfrag + off) = h4;
        *(s4v*)(Cfrag + (size_t)okc * 4096 + off) = l4;
      }
    }
  }
}

// ---------------------------------------------------------------------------
// g4mf: MFMA split-3 pair-tile delta + symmetrize + x2 + pass-0 histogram.
// A staged from o1 fp32 via LDS (split in registers — bit-identical to the
// old afrag path); B frags from dfrag (dec1_w, pre-split).
// Waves 0/1: delta(I,J); waves 2/3: delta(J,I) -> LDS exchange.
// ---------------------------------------------------------------------------
__global__ void __launch_bounds__(256) g4mf(
    const float* __restrict__ o1,    // [B][128][400] fp32 (out2b)
    const short* __restrict__ wfrag, // dec1_w frags, 2 planes of PLA
    const float* __restrict__ bias,  // dec1_b
    float* __restrict__ xf,          // in-place -> x2
    unsigned* __restrict__ ghist)
{
  __shared__ float S[2 * 64 * 36];   // SI|SJ staging; D2 (64x68=4352) aliases
  __shared__ unsigned hist[8][256];
  const int b = blockIdx.y;
  int p = blockIdx.x, bi = 0;
  while (p >= NT - bi) { p -= NT - bi; ++bi; }
  const int bj = bi + p;
  const int I0 = bi * 64, J0 = bj * 64;
  const bool diag = (bi == bj);

  o1 += (size_t)b * HID * NNODE;
  xf += (size_t)b * NN;
  unsigned* gh = ghist + b * 256;

  const int tid = threadIdx.x;
  const int lane = tid & 63, wave = tid >> 6;
  const int wq = wave & 1;
  const bool d1 = wave < 2;
  const int Bt = (d1 ? bj : bi) * 4;   // B ntile base (global, in wfrag)
  const int quad = lane >> 4, l15 = lane & 15;

  float* SI = S;
  float* SJ = S + 64 * 36;
  const float* Sp = d1 ? SI : SJ;

  for (int i = tid; i < 8 * 256; i += 256) ((unsigned*)hist)[i] = 0u;

  f4v acc[2][4];
#pragma unroll
  for (int i = 0; i < 2; ++i)
#pragma unroll
    for (int j = 0; j < 4; ++j) acc[i][j] = (f4v){0.f, 0.f, 0.f, 0.f};

  for (int c = 0; c < 4; ++c) {
    const int k0 = c << 5;
    if (c) __syncthreads();
    // ---- stage SI/SJ: S[m 64][k 36pad] from o1[k][m] ----
    {
      const int kk = tid >> 4;           // 0..15
      const int m4 = (tid & 15) << 2;
#pragma unroll
      for (int half = 0; half < 2; ++half) {
        const int k = k0 + kk + (half << 4);
        const float* row = o1 + (size_t)k * NNODE;
        float4 vi = {0.f,0.f,0.f,0.f}, vj = {0.f,0.f,0.f,0.f};
        if (I0 + m4 + 4 <= NNODE) vi = *(const float4*)(row + I0 + m4);
        else {
          float* pv = (float*)&vi;
#pragma unroll
          for (int j = 0; j < 4; ++j) if (I0 + m4 + j < NNODE) pv[j] = row[I0 + m4 + j];
        }
        if (J0 + m4 + 4 <= NNODE) vj = *(const float4*)(row + J0 + m4);
        else {
          float* pv = (float*)&vj;
#pragma unroll
          for (int j = 0; j < 4; ++j) if (J0 + m4 + j < NNODE) pv[j] = row[J0 + m4 + j];
        }
        const int kc2 = kk + (half << 4);
        SI[(m4 + 0) * 36 + kc2] = vi.x; SI[(m4 + 1) * 36 + kc2] = vi.y;
        SI[(m4 + 2) * 36 + kc2] = vi.z; SI[(m4 + 3) * 36 + kc2] = vi.w;
        SJ[(m4 + 0) * 36 + kc2] = vj.x; SJ[(m4 + 1) * 36 + kc2] = vj.y;
        SJ[(m4 + 2) * 36 + kc2] = vj.z; SJ[(m4 + 3) * 36 + kc2] = vj.w;
      }
    }
    __syncthreads();

    // ---- B frags from global, A from LDS (split in registers) ----
    s8v bhi[4], blo[4];
#pragma unroll
    for (int nt = 0; nt < 4; ++nt) {
      const int ntg = Bt + nt;
      const size_t off = (((size_t)c * 28 + ntg) * 64 + lane) * 8;
      bhi[nt] = *(const s8v*)(wfrag + off);
      blo[nt] = *(const s8v*)(wfrag + PLA + off);
    }
#pragma unroll
    for (int mt = 0; mt < 2; ++mt) {
      const int m = ((wq << 1) + mt) * 16 + l15;
      const f4v a0 = *(const f4v*)&Sp[m * 36 + (quad << 3)];
      const f4v a1 = *(const f4v*)&Sp[m * 36 + (quad << 3) + 4];
      s8v ah, al;
#pragma unroll
      for (int j = 0; j < 4; ++j) {
        short h0 = f2bf(a0[j]); ah[j] = h0; al[j] = f2bf(a0[j] - bf2f(h0));
        short h1 = f2bf(a1[j]); ah[j + 4] = h1; al[j + 4] = f2bf(a1[j] - bf2f(h1));
      }
#pragma unroll
      for (int nt = 0; nt < 4; ++nt) {
        acc[mt][nt] = __builtin_amdgcn_mfma_f32_16x16x32_bf16(ah, bhi[nt], acc[mt][nt], 0, 0, 0);
        acc[mt][nt] = __builtin_amdgcn_mfma_f32_16x16x32_bf16(ah, blo[nt], acc[mt][nt], 0, 0, 0);
        acc[mt][nt] = __builtin_amdgcn_mfma_f32_16x16x32_bf16(al, bhi[nt], acc[mt][nt], 0, 0, 0);
      }
    }
  }
  __syncthreads();

  float (*D2)[68] = (float(*)[68])S;
  // waves 2/3: dump delta2[m'][n'] to LDS
  if (!d1) {
#pragma unroll
    for (int mt = 0; mt < 2; ++mt) {
      const int mb = (wq << 5) + (mt << 4) + (quad << 2);
#pragma unroll
      for (int nt = 0; nt < 4; ++nt) {
        const int nn = (nt << 4) + l15;
        const f4v a = acc[mt][nt];
#pragma unroll
        for (int reg = 0; reg < 4; ++reg) D2[mb + reg][nn] = a[reg];
      }
    }
  }
  __syncthreads();

  // waves 0/1: form x2 tile (I,J), write both (I,J) and (J,I), histogram
  if (d1) {
    const int rep = tid & 7;
#pragma unroll
    for (int mt = 0; mt < 2; ++mt) {
      const int a0 = (wq << 5) + (mt << 4) + (quad << 2);
#pragma unroll
      for (int nt = 0; nt < 4; ++nt) {
        const int nn = (nt << 4) + l15;
        const int gj = J0 + nn;
        const f4v d1v = acc[mt][nt];
        const f4v d2t = *(const f4v*)&D2[nn][a0];
        f4v vv;
#pragma unroll
        for (int reg = 0; reg < 4; ++reg) {
          const int gi = I0 + a0 + reg;
          float v = 0.f;
          if (gi < NNODE && gj < NNODE) {
            v = xf[(size_t)gi * NNODE + gj];
            if (gi != gj)
              v += 0.5f * (d1v[reg] + d2t[reg] + bias[gj] + bias[gi]);
            atomicAdd(&hist[rep][tokey(v) >> 24], diag ? 1u : 2u);
          }
          vv[reg] = v;
        }
#pragma unroll
        for (int reg = 0; reg < 4; ++reg) {
          const int gi = I0 + a0 + reg;
          if (gi < NNODE && gj < NNODE) xf[(size_t)gi * NNODE + gj] = vv[reg];
        }
        if (!diag && gj < NNODE && (I0 + a0 + 4 <= NNODE)) {
          *(float4*)(xf + (size_t)gj * NNODE + I0 + a0) = *(float4*)&vv;
        }
      }
    }
  }
  __syncthreads();
  if (tid < 256) {
    const unsigned s = hist[0][tid] + hist[1][tid] + hist[2][tid] + hist[3][tid]
                     + hist[4][tid] + hist[5][tid] + hist[6][tid] + hist[7][tid];
    if (s) atomicAdd(&gh[tid], s);
  }
}

// ---------------------------------------------------------------------------
__global__ void denom_k(const float* __restrict__ x, float* __restrict__ denom) {
  int b = threadIdx.x;
  if (b < BATCH) {
    float v = x[(size_t)b * NN];
    denom[b] = 0.5f * logf((1.0f + v + EPSF) / (1.0f - v + EPSF));
  }
}

// ---------------------------------------------------------------------------
__global__ void tz_init(unsigned* __restrict__ ghist, unsigned* __restrict__ sprefix,
                        int* __restrict__ sk, int* __restrict__ eqcnt,
                        float* __restrict__ deg) {
  int t = blockIdx.x * 256 + threadIdx.x;
  if (t < BATCH * 256) ghist[t] = 0u;
  if (t < BATCH) { sprefix[t] = 0u; sk[t] = KSEL; eqcnt[t] = 0; }
  if (t < BATCH * NNODE) deg[t] = 0.f;
}

template<int PASS>
__global__ void __launch_bounds__(256) thist(const float* __restrict__ x2,
                                             const unsigned* __restrict__ sprefix,
                                             unsigned* __restrict__ ghist) {
  constexpr int shift = 24 - 8 * PASS;
  __shared__ unsigned h[8][256];
  const int b  = blockIdx.y;
  const int sb = blockIdx.x;
  const int tid = threadIdx.x;
  for (int i = tid; i < 8 * 256; i += 256) ((unsigned*)h)[i] = 0u;
  __syncthreads();

  const unsigned prefix = sprefix[b];
  const unsigned pmask  = 0xFFFFFFFFu << (shift + 8);
  const int rep = tid & 7;
  const float4* p4 = (const float4*)(x2 + (size_t)b * NN);
  const int i0 = sb * (SEG / 4), i1 = i0 + (SEG / 4);
  for (int i = i0 + tid; i < i1; i += 256) {
    float4 v = p4[i];
    unsigned k0 = tokey(v.x), k1 = tokey(v.y), k2 = tokey(v.z), k3 = tokey(v.w);
    if ((k0 & pmask) == prefix) atomicAdd(&h[rep][(k0 >> shift) & 255u], 1u);
    if ((k1 & pmask) == prefix) atomicAdd(&h[rep][(k1 >> shift) & 255u], 1u);
    if ((k2 & pmask) == prefix) atomicAdd(&h[rep][(k2 >> shift) & 255u], 1u);
    if ((k3 & pmask) == prefix) atomicAdd(&h[rep][(k3 >> shift) & 255u], 1u);
  }
  __syncthreads();
  if (tid < 256) {
    unsigned s = h[0][tid] + h[1][tid] + h[2][tid] + h[3][tid]
               + h[4][tid] + h[5][tid] + h[6][tid] + h[7][tid];
    if (s) atomicAdd(&ghist[b * 256 + tid], s);
  }
}

template<int PASS>
__global__ void __launch_bounds__(256) tpick(unsigned* __restrict__ ghist,
                                             unsigned* __restrict__ sprefix,
                                             int* __restrict__ sk,
                                             unsigned* __restrict__ tau,
                                             int* __restrict__ rrem) {
  constexpr int shift = 24 - 8 * PASS;
  const int b = blockIdx.x;
  __shared__ unsigned h[256];
  h[threadIdx.x] = ghist[b * 256 + threadIdx.x];
  __syncthreads();
  if (threadIdx.x == 0) {
    int k = sk[b];
    unsigned byte = 0u;
    for (int bin = 255; bin >= 0; --bin) {
      int c = (int)h[bin];
      if (c >= k) { byte = (unsigned)bin; break; }
      k -= c;
    }
    unsigned np = sprefix[b] | (byte << shift);
    sprefix[b] = np; sk[b] = k;
    if (PASS == 3) { tau[b] = np; rrem[b] = k; }
  }
  ghist[b * 256 + threadIdx.x] = 0u;
}

// ---------------------------------------------------------------------------
// build_kc: A = x2 masked (key > tau), tie gathering, AND per-column sums
// (fuses old deg_k). Block = (16-row group, sample). deg zeroed in tz_init.
// ---------------------------------------------------------------------------
__global__ void __launch_bounds__(256) build_kc(
    const float* __restrict__ x2, const unsigned* __restrict__ tau,
    float* __restrict__ A, float* __restrict__ deg,
    int* __restrict__ eqcnt, int* __restrict__ eqidx) {
  __shared__ float cs[NNODE];
  const int b = blockIdx.y, rg = blockIdx.x;
  const int tid = threadIdx.x;
  for (int i = tid; i < NNODE; i += 256) cs[i] = 0.f;
  __syncthreads();
  const unsigned tk = tau[b];
  const size_t base = (size_t)b * NN + (size_t)rg * 6400;
  for (int u = 0; u < 25; ++u) {
    const int t = u * 256 + tid;          // < 6400 = 16 rows * 400 cols
    const float v = x2[base + t];
    const unsigned key = tokey(v);
    const float a = (key > tk) ? v : 0.f;
    A[base + t] = a;
    if (key == tk) {
      int p = atomicAdd(&eqcnt[b], 1);
      if (p < EQCAP) eqidx[b * EQCAP + p] = rg * 6400 + t;
    }
    if (a != 0.f) atomicAdd(&cs[t % NNODE], a);
  }
  __syncthreads();
  for (int j = tid; j < NNODE; j += 256)
    if (cs[j] != 0.f) atomicAdd(&deg[b * NNODE + j], cs[j]);
}

// include the first rrem tie elements (ascending flat index); patch deg too
__global__ void eqfix_k(float* __restrict__ A, const float* __restrict__ x2,
                        float* __restrict__ deg,
                        const int* __restrict__ eqcnt, const int* __restrict__ eqidx,
                        const int* __restrict__ rrem) {
  int b = blockIdx.x;
  int cnt = eqcnt[b]; if (cnt > EQCAP) cnt = EQCAP;
  int r = rrem[b];
  for (int t = threadIdx.x; t < cnt; t += 256) {
    int idx = eqidx[b * EQCAP + t];
    int rank = 0;
    for (int u = 0; u < cnt; ++u) rank += (eqidx[b * EQCAP + u] < idx) ? 1 : 0;
    if (rank < r) {
      float v = x2[(size_t)b * NN + idx];
      A[(size_t)b * NN + idx] = v;
      atomicAdd(&deg[b * NNODE + idx % NNODE], v);
    }
  }
}

// diag fill (exact gcn_norm semantics: fill only if A[j][j]==0, deg += 1) + dinv
__global__ void dinv_k(float* __restrict__ A, const float* __restrict__ deg,
                       float* __restrict__ dinv) {
  int t = blockIdx.x * blockDim.x + threadIdx.x;
  if (t >= BATCH * NNODE) return;
  int b = t / NNODE, j = t - b * NNODE;
  float d = deg[t];
  size_t o = (size_t)b * NN + (size_t)j * NNODE + j;
  if (A[o] == 0.f) { A[o] = 1.0f; d += 1.0f; }
  dinv[t] = (d == 0.f) ? 0.f : 1.0f / sqrtf(d);
}

__global__ void head_k(const float* __restrict__ h2, const float* __restrict__ fc_w,
                       const float* __restrict__ fc_b, float* __restrict__ out) {
  int b = blockIdx.x;
  int f = threadIdx.x;
  float s = 0.f;
  const float* p = h2 + (size_t)b * NNODE * HID + f;
  for (int j = 0; j < NNODE; ++j) s += p[(size_t)j * HID];
  float pv = fmaxf(s / (float)NNODE, 0.f);
  __shared__ float r0[128], r1[128];
  r0[f] = pv * fc_w[f * 2 + 0];
  r1[f] = pv * fc_w[f * 2 + 1];
  __syncthreads();
  for (int sft = 64; sft > 0; sft >>= 1) {
    if (f < sft) { r0[f] += r0[f + sft]; r1[f] += r1[f + sft]; }
    __syncthreads();
  }
  if (f == 0) {
    out[b * 2 + 0] = r0[0] + fc_b[0];
    out[b * 2 + 1] = r1[0] + fc_b[1];
  }
}

// ---------------------------------------------------------------------------
extern "C" void kernel_launch(void* const* d_in, const int* in_sizes, int n_in,
                              void* d_out, int out_size, void* d_ws, size_t ws_size,
                              hipStream_t stream) {
  const float* x      = (const float*)d_in[0];
  const float* enc1_w = (const float*)d_in[2];
  const float* enc1_b = (const float*)d_in[3];
  const float* enc2_w = (const float*)d_in[4];
  const float* enc2_b = (const float*)d_in[5];
  const float* dec2_w = (const float*)d_in[6];
  const float* dec2_b = (const float*)d_in[7];
  const float* dec1_w = (const float*)d_in[8];
  const float* dec1_b = (const float*)d_in[9];
  const float* gcn1_w = (const float*)d_in[10];
  const float* gcn1_b = (const float*)d_in[11];
  const float* gcn2_w = (const float*)d_in[12];
  const float* gcn2_b = (const float*)d_in[13];
  const float* fc_w   = (const float*)d_in[14];
  const float* fc_b   = (const float*)d_in[15];
  float* out = (float*)d_out;
  (void)in_sizes; (void)n_in; (void)out_size; (void)ws_size;

  float* ws = (float*)d_ws;
  size_t off = 0;
  auto take = [&](size_t n) { float* p = ws + off; off += (n + 63) & ~(size_t)63; return p; };
  float* xf   = take((size_t)BATCH * NN);          // xf -> x2 (in place)
  float* dl   = take((size_t)BATCH * NN);          // A (sparsified)
  float* o1   = take((size_t)BATCH * HID * NNODE); // out1 -> out2b; later xwfrag alias
  float* o2   = take((size_t)BATCH * HID * HID);
  float* hbuf = take((size_t)BATCH * NNODE * HID); // h -> h2
  float* denom = take(BATCH);
  float* dinv  = take((size_t)BATCH * NNODE);
  float* deg   = take((size_t)BATCH * NNODE);
  unsigned* tau = (unsigned*)take(BATCH);
  int* rrem  = (int*)take(BATCH);
  int* eqcnt = (int*)take(BATCH);
  int* eqidx = (int*)take((size_t)BATCH * EQCAP);
  unsigned* ghist   = (unsigned*)take((size_t)BATCH * 256);
  unsigned* sprefix = (unsigned*)take(BATCH);
  int*      sk      = (int*)take(BATCH);
  short* w1frag = (short*)take((size_t)FRAGS + 64);          // gcn1_w, 2 planes K448
  short* w2frag = (short*)take((size_t)4 * 4096 + 64);       // gcn2_w, 2 planes K128
  short* e1frag = (short*)take((size_t)FRAGS + 64);          // enc1_w
  short* e2frag = (short*)take((size_t)FRAGS + 64);          // enc2_w
  short* dfrag  = (short*)take((size_t)PLA + 64);            // dec1_w (2*PLA shorts)
  short* xwfrag = (short*)o1;          // aliases dead o1 (post-g4mf)
  const long sXW = 2L * FRAGS;

  tz_init<<<200, 256, 0, stream>>>(ghist, sprefix, sk, eqcnt, deg);
  denom_k<<<1, BATCH, 0, stream>>>(x, denom);
  bsplitN<<<224, 256, 0, stream>>>(gcn1_w, NNODE, 448, HID, 128, w1frag);
  bsplitN<<<64,  256, 0, stream>>>(gcn2_w, HID, 128, HID, 128, w2frag);
  bsplitN<<<224, 256, 0, stream>>>(enc1_w, NNODE, 448, HID, 128, e1frag);
  bsplitN<<<224, 256, 0, stream>>>(enc2_w, NNODE, 448, HID, 128, e2frag);
  bsplitN<<<224, 256, 0, stream>>>(dec1_w, HID, 128, NNODE, 448, dfrag);

  // G1 (+fused xf): reads raw x, computes/stores xf, o1 = (relu(xf@enc1_w+b))^T
  mfgemm<false, false, true, true, false, true, true><<<dim3(7, BATCH), 256, 0, stream>>>(
      x, NN, NNODE, e1frag, 0, KC400, enc1_b, nullptr,
      o1, (long)HID * NNODE, NNODE, nullptr, 0, 0, denom, xf, NNODE, NNODE);
  // G2: o2 = relu(o1 @ enc2_w + b)
  mfgemm<false, false, true, true, false, false, false><<<dim3(2, BATCH), 256, 0, stream>>>(
      o1, (long)HID * NNODE, NNODE, e2frag, 0, KC400, enc2_b, nullptr,
      o2, (long)HID * HID, HID, nullptr, 0, 0, nullptr, nullptr, HID, NNODE);
  // G3: out2b = relu(o2 @ dec2_w + b + o1), in-place (fp32)
  gemm64<false, true, true, true, false><<<dim3(7, 2, BATCH), 256, 0, stream>>>(
      o2, (long)HID * HID, HID, dec2_w, 0, NNODE, dec2_b,
      o1, (long)HID * NNODE, o1, (long)HID * NNODE, NNODE, HID, NNODE, HID);

  // fused delta + symmetrize + x2 + pass-0 histogram (stages o1 directly)
  g4mf<<<dim3(NT * (NT + 1) / 2, BATCH), 256, 0, stream>>>(o1, dfrag, dec1_b, xf, ghist);

  tpick<0><<<BATCH, 256, 0, stream>>>(ghist, sprefix, sk, tau, rrem);
  thist<1><<<dim3(TSPLIT, BATCH), 256, 0, stream>>>(xf, sprefix, ghist);
  tpick<1><<<BATCH, 256, 0, stream>>>(ghist, sprefix, sk, tau, rrem);
  thist<2><<<dim3(TSPLIT, BATCH), 256, 0, stream>>>(xf, sprefix, ghist);
  tpick<2><<<BATCH, 256, 0, stream>>>(ghist, sprefix, sk, tau, rrem);
  thist<3><<<dim3(TSPLIT, BATCH), 256, 0, stream>>>(xf, sprefix, ghist);
  tpick<3><<<BATCH, 256, 0, stream>>>(ghist, sprefix, sk, tau, rrem);

  // A build + column sums (fused deg), tie fix (patches deg), diag-fill + dinv
  build_kc<<<dim3(25, BATCH), 256, 0, stream>>>(xf, tau, dl, deg, eqcnt, eqidx);
  eqfix_k<<<BATCH, 256, 0, stream>>>(dl, xf, deg, eqcnt, eqidx, rrem);
  dinv_k<<<(BATCH * NNODE + 255) / 256, 256, 0, stream>>>(dl, deg, dinv);

  // ---- post-top-k GCN: MFMA bf16 split-3 ----
  mfgemm<false, true, false, false, true, false, false><<<dim3(7, BATCH), 256, 0, stream>>>(
      xf, NN, NNODE, w1frag, 0, KC400, nullptr, dinv,
      nullptr, 0, 128, xwfrag, sXW, KC400, nullptr, nullptr, NNODE, NNODE);
  mfgemm<true, false, true, true, true, false, false><<<dim3(7, BATCH), 256, 0, stream>>>(
      dl, NN, NNODE, xwfrag, sXW, KC400, gcn1_b, dinv,
      hbuf, (long)NNODE * HID, HID, nullptr, 0, 0, nullptr, nullptr, NNODE, NNODE);
  mfgemm<false, true, false, false, true, false, false><<<dim3(7, BATCH), 256, 0, stream>>>(
      hbuf, (long)NNODE * HID, HID, w2frag, 0, 4, nullptr, dinv,
      nullptr, 0, 128, xwfrag, sXW, KC400, nullptr, nullptr, NNODE, HID);
  mfgemm<true, false, true, false, true, false, false><<<dim3(7, BATCH), 256, 0, stream>>>(
      dl, NN, NNODE, xwfrag, sXW, KC400, gcn2_b, dinv,
      hbuf, (long)NNODE * HID, HID, nullptr, 0, 0, nullptr, nullptr, NNODE, NNODE);

  head_k<<<BATCH, HID, 0, stream>>>(hbuf, fc_w, fc_b, out);
}